// Round 3
// baseline (1646.944 us; speedup 1.0000x reference)
//
#include <hip/hip_runtime.h>
#include <stdio.h>
#include <stdint.h>

typedef __attribute__((ext_vector_type(8))) short short8;     // 8 x bf16 bits (4 VGPRs)
typedef __attribute__((ext_vector_type(4))) float f32x4;      // MFMA accum
typedef __attribute__((ext_vector_type(4))) unsigned short ushort4v;

__device__ __forceinline__ unsigned short f2bf(float f) {
  unsigned int u = __builtin_bit_cast(unsigned int, f);
  u = u + 0x7FFFu + ((u >> 16) & 1u);   // RNE
  return (unsigned short)(u >> 16);
}
__device__ __forceinline__ float bf2f(unsigned short h) {
  unsigned int u = ((unsigned int)h) << 16;
  return __builtin_bit_cast(float, u);
}

// ---------------- weight transpose+cast (+zero pad) : out[n][k] = in[k][n] ----------------
__global__ void k_transpose_cast(const float* __restrict__ in, unsigned short* __restrict__ out,
                                 int Nin, int Kin, int ldo) {
  int k = blockIdx.x * blockDim.x + threadIdx.x;
  int n = blockIdx.y;
  if (k >= ldo) return;
  float v = (n < Nin && k < Kin) ? in[(size_t)k * Nin + n] : 0.f;
  out[(size_t)n * ldo + k] = f2bf(v);
}

// ---------------- att layer 1: h = relu(t[b]*W2a[j] + b2a[j]) -> bf16 [2048x1024] ----------------
__global__ void k_att_l1(const float* __restrict__ tar, const float* __restrict__ W2a,
                         const float* __restrict__ b2a, unsigned short* __restrict__ out) {
  int id = blockIdx.x * 256 + threadIdx.x;   // 2048*1024
  int b = id >> 10, j = id & 1023;
  out[id] = f2bf(fmaxf(tar[b] * W2a[j] + b2a[j], 0.f));
}

// ---------------- v2s cast to bf16, K padded 312->320 ----------------
__global__ void k_v2s_cast(const float* __restrict__ v2s, unsigned short* __restrict__ out) {
  int id = blockIdx.x * 256 + threadIdx.x;   // 2048*320
  int r = id / 320, c = id - r * 320;
  out[id] = (c < 312) ? f2bf(v2s[(size_t)r * 312 + c]) : (unsigned short)0;
}

// ---------------- generic bf16 GEMM: C[M x N] = act(A[M x K] @ BT[N x K]^T + bias) ----------------
// 128x128 tile, BK=32, 256 thr (2x2 waves of 64x64), LDS slot-swizzled (2-way conflicts = free)
__device__ __forceinline__ int lds_off(int row, int g) {
  int slot = (g + (row >> 1)) & 3;            // spreads 8 rows over 8 bank-quads
  return row * 32 + slot * 8;                 // ushort units
}

template<bool RELU, bool OUTBF16>
__global__ __launch_bounds__(256, 2)
void k_gemm_bt(const unsigned short* __restrict__ A, const unsigned short* __restrict__ B,
               const float* __restrict__ bias, int bias_n, int nNt, int N_store, int K,
               void* __restrict__ outp, int ldo, int remap) {
  __shared__ __align__(16) unsigned short As[128 * 32];
  __shared__ __align__(16) unsigned short Bs[128 * 32];
  int d = blockIdx.x, nwg = gridDim.x;
  int L = d;
  if (remap) { int q = nwg >> 3; L = (d & 7) * q + (d >> 3); }  // only used when nwg % 8 == 0
  int mt = L / nNt, nt = L - mt * nNt;
  size_t m0 = (size_t)mt * 128, n0 = (size_t)nt * 128;
  int tid = threadIdx.x, lane = tid & 63;
  int w = tid >> 6, wr = w >> 1, wc = w & 1;
  int sr = tid >> 2, sg = tid & 3;            // staging: row sr/sr+64, 16B chunk sg
  const unsigned short* Ap0 = A + (m0 + sr) * K + sg * 8;
  const unsigned short* Ap1 = A + (m0 + sr + 64) * K + sg * 8;
  const unsigned short* Bp0 = B + (n0 + sr) * K + sg * 8;
  const unsigned short* Bp1 = B + (n0 + sr + 64) * K + sg * 8;
  int wo0 = lds_off(sr, sg), wo1 = lds_off(sr + 64, sg);
  int kg = lane >> 4, l15 = lane & 15;
  int aoff = lds_off(wr * 64 + l15, kg);      // slot invariant under +16-row steps
  int boff = lds_off(wc * 64 + l15, kg);

  f32x4 acc[4][4];
  #pragma unroll
  for (int i = 0; i < 4; ++i)
    #pragma unroll
    for (int j = 0; j < 4; ++j) acc[i][j] = (f32x4)(0.f);

  short8 ra0 = *(const short8*)Ap0;
  short8 ra1 = *(const short8*)Ap1;
  short8 rb0 = *(const short8*)Bp0;
  short8 rb1 = *(const short8*)Bp1;

  for (int k0 = 0; k0 < K; k0 += 32) {
    __syncthreads();                           // LDS free (prev MFMAs done)
    *(short8*)&As[wo0] = ra0; *(short8*)&As[wo1] = ra1;
    *(short8*)&Bs[wo0] = rb0; *(short8*)&Bs[wo1] = rb1;
    __syncthreads();
    if (k0 + 32 < K) {                         // issue next-tile loads early (overlap MFMA)
      ra0 = *(const short8*)(Ap0 + k0 + 32);
      ra1 = *(const short8*)(Ap1 + k0 + 32);
      rb0 = *(const short8*)(Bp0 + k0 + 32);
      rb1 = *(const short8*)(Bp1 + k0 + 32);
    }
    short8 af[4], bfr[4];
    #pragma unroll
    for (int mi = 0; mi < 4; ++mi) af[mi] = *(const short8*)&As[aoff + mi * 512];
    #pragma unroll
    for (int ni = 0; ni < 4; ++ni) bfr[ni] = *(const short8*)&Bs[boff + ni * 512];
    #pragma unroll
    for (int mi = 0; mi < 4; ++mi)
      #pragma unroll
      for (int ni = 0; ni < 4; ++ni)
        acc[mi][ni] = __builtin_amdgcn_mfma_f32_16x16x32_bf16(af[mi], bfr[ni], acc[mi][ni], 0, 0, 0);
  }

  #pragma unroll
  for (int ni = 0; ni < 4; ++ni) {
    int colg = (int)n0 + wc * 64 + ni * 16 + l15;
    if (colg < N_store) {
      float bs = bias ? (colg < bias_n ? bias[colg] : 0.f) : 0.f;
      #pragma unroll
      for (int mi = 0; mi < 4; ++mi) {
        #pragma unroll
        for (int r2 = 0; r2 < 4; ++r2) {
          size_t rowg = m0 + wr * 64 + mi * 16 + kg * 4 + r2;   // C/D: row=(l>>4)*4+r, col=l&15
          float v = acc[mi][ni][r2] + bs;
          if (RELU) v = fmaxf(v, 0.f);
          if (OUTBF16) ((unsigned short*)outp)[rowg * ldo + colg] = f2bf(v);
          else         ((float*)outp)[rowg * ldo + colg] = v;
        }
      }
    }
  }
}

// ------- H1c[r_local] = relu(V1[src] + A1p[arow]) -> bf16  (b1a pre-folded into A1p) -------
__global__ void k_build_h1(const float* __restrict__ V1, const float* __restrict__ A1p,
                           const int* __restrict__ idx, unsigned short* __restrict__ H1c,
                           int rbase) {
  int row = rbase + blockIdx.x;                // global row 0..133119
  int src, arow;
  if (row < 2048) { src = row; arow = row; }   // rows 0..2047 = query
  else {
    int g = row - 2048; arow = g >> 6;
    int s = idx[g];
    src = s < 0 ? 0 : (s > 2047 ? 2047 : s);
  }
  int j = threadIdx.x * 4;
  float4 v = *(const float4*)(V1 + (size_t)src * 1024 + j);
  float4 a = *(const float4*)(A1p + (size_t)arow * 1024 + j);
  ushort4v o;
  o.x = f2bf(fmaxf(v.x + a.x, 0.f));
  o.y = f2bf(fmaxf(v.y + a.y, 0.f));
  o.z = f2bf(fmaxf(v.z + a.z, 0.f));
  o.w = f2bf(fmaxf(v.w + a.w, 0.f));
  *(ushort4v*)(H1c + (size_t)blockIdx.x * 1024 + j) = o;
}

// ---------------- logits[b,k] = dot(P[b], P[2048 + b*64 + k]) / T  (P is bf16) ----------------
__global__ void k_dot(const unsigned short* __restrict__ P, float* __restrict__ out) {
  __shared__ float q[128];
  int b = blockIdx.x, t = threadIdx.x;
  if (t < 128) q[t] = bf2f(P[(size_t)b * 128 + t]);
  __syncthreads();
  int k = t >> 2, part = t & 3;
  const unsigned short* row = P + (size_t)(2048 + b * 64 + k) * 128 + part * 32;
  const float* qp = q + part * 32;
  float s = 0.f;
  #pragma unroll
  for (int j = 0; j < 32; j += 8) {
    short8 pv = *(const short8*)(row + j);
    #pragma unroll
    for (int e = 0; e < 8; ++e)
      s += bf2f((unsigned short)pv[e]) * qp[j + e];
  }
  s += __shfl_xor(s, 1);
  s += __shfl_xor(s, 2);
  if (part == 0) out[(size_t)b * 64 + k] = s * (float)(1.0 / 0.12);
}

extern "C" void kernel_launch(void* const* d_in, const int* in_sizes, int n_in,
                              void* d_out, int out_size, void* d_ws, size_t ws_size,
                              hipStream_t stream) {
  const float* v2s = (const float*)d_in[0];
  const float* tar = (const float*)d_in[1];
  const int*   sidx = (const int*)d_in[2];
  const float* W2a = (const float*)d_in[3];
  const float* b2a = (const float*)d_in[4];
  const float* W2b = (const float*)d_in[5];
  const float* b2b = (const float*)d_in[6];
  const float* W2c = (const float*)d_in[7];
  const float* b2c = (const float*)d_in[8];
  const float* W1a = (const float*)d_in[9];
  const float* b1a = (const float*)d_in[10];
  const float* W1b = (const float*)d_in[11];
  const float* b1b = (const float*)d_in[12];
  const float* W1c = (const float*)d_in[13];
  const float* b1c = (const float*)d_in[14];
  float* out = (float*)d_out;

  // ---- workspace layout: persistent region + overlay (early att-MLP temps / late chunk bufs)
  const int NCH = 16, R = 133120 / NCH;       // R = 8320 rows per chunk, 65 m-tiles
  char* ws = (char*)d_ws;
  size_t off = 0;
  auto alloc = [&](size_t bytes) -> char* {
    char* p = ws + off; off += (bytes + 255) & ~(size_t)255; return p;
  };
  // persistent
  unsigned short* W1bT = (unsigned short*)alloc(2048ull * 1024 * 2);  // [2048][1024]
  unsigned short* W1cT = (unsigned short*)alloc(128ull * 2048 * 2);   // [128][2048]
  float*          V1   = (float*)alloc(2048ull * 1024 * 4);           // v2s @ W1a
  float*          A1p  = (float*)alloc(2048ull * 1024 * 4);           // att @ W1a + b1a
  unsigned short* Pb   = (unsigned short*)alloc(133120ull * 128 * 2); // bf16 projections
  // overlay
  size_t O = off;
  // early (dead before chunk loop starts)
  off = O;
  unsigned short* W1aT = (unsigned short*)alloc(1024ull * 320 * 2);   // [1024][320]  (K-pad)
  unsigned short* v2sb = (unsigned short*)alloc(2048ull * 320 * 2);
  unsigned short* attb = (unsigned short*)alloc(2048ull * 320 * 2);
  unsigned short* W2bT = (unsigned short*)alloc(2048ull * 1024 * 2);
  unsigned short* W2cT = (unsigned short*)alloc(384ull * 2048 * 2);   // [384][2048]  (N-pad)
  unsigned short* h_a  = (unsigned short*)alloc(2048ull * 1024 * 2);
  unsigned short* h2a  = (unsigned short*)alloc(2048ull * 2048 * 2);
  size_t early_end = off;
  // late (chunk buffers, overlap early)
  off = O;
  unsigned short* H1c = (unsigned short*)alloc((size_t)R * 1024 * 2);
  unsigned short* H2c = (unsigned short*)alloc((size_t)R * 2048 * 2);
  size_t needed = (off > early_end) ? off : early_end;
  fprintf(stderr, "[kernel_launch] ws_size=%zu needed=%zu\n", ws_size, needed);
  if (needed > ws_size) {   // diagnostic fallback: zero output, no OOB write
    hipMemsetAsync(d_out, 0, (size_t)out_size * 4, stream);
    return;
  }

  dim3 blk(256);
  // weight prep
  k_transpose_cast<<<dim3(4, 2048), blk, 0, stream>>>(W2b, W2bT, 2048, 1024, 1024);
  k_transpose_cast<<<dim3(8, 384),  blk, 0, stream>>>(W2c, W2cT, 312, 2048, 2048);
  k_transpose_cast<<<dim3(2, 1024), blk, 0, stream>>>(W1a, W1aT, 1024, 312, 320);
  k_transpose_cast<<<dim3(4, 2048), blk, 0, stream>>>(W1b, W1bT, 2048, 1024, 1024);
  k_transpose_cast<<<dim3(8, 128),  blk, 0, stream>>>(W1c, W1cT, 128, 2048, 2048);
  k_att_l1<<<8192, blk, 0, stream>>>(tar, W2a, b2a, h_a);
  k_v2s_cast<<<2560, blk, 0, stream>>>(v2s, v2sb);
  // att MLP: h2a = relu(h_a @ W2b + b2b); attb = relu(h2a @ W2c + b2c) (cols 312..319 = 0)
  k_gemm_bt<true,  true ><<<256, blk, 0, stream>>>(h_a,  W2bT, b2b, 2048, 16, 2048, 1024, h2a,  2048, 1);
  k_gemm_bt<true,  true ><<<48,  blk, 0, stream>>>(h2a,  W2cT, b2c, 312,  3,  320,  2048, attb, 320,  1);
  // layer-1 factored: V1 = v2s@W1a (no bias); A1p = att@W1a + b1a  (f32 out, no act)
  k_gemm_bt<false, false><<<128, blk, 0, stream>>>(v2sb, W1aT, nullptr, 0,  8, 1024, 320, V1,  1024, 1);
  k_gemm_bt<false, false><<<128, blk, 0, stream>>>(attb, W1aT, b1a, 1024,  8, 1024, 320, A1p, 1024, 1);
  // chunked: build H1 -> layer2 -> layer3
  for (int c = 0; c < NCH; ++c) {
    int rbase = c * R;
    k_build_h1<<<R, blk, 0, stream>>>(V1, A1p, sidx, H1c, rbase);
    k_gemm_bt<true, true><<<(R / 128) * 16, blk, 0, stream>>>(H1c, W1bT, b1b, 2048, 16, 2048, 1024, H2c, 2048, 1);
    k_gemm_bt<true, true><<<(R / 128), blk, 0, stream>>>(H2c, W1cT, b1c, 128, 1, 128, 2048,
                                                          Pb + (size_t)rbase * 128, 128, 0);
  }
  // logits
  k_dot<<<2048, blk, 0, stream>>>(Pb, out);
}

// Round 4
// 1173.381 us; speedup vs baseline: 1.4036x; 1.4036x over previous
//
#include <hip/hip_runtime.h>
#include <stdio.h>
#include <stdint.h>

typedef __attribute__((ext_vector_type(8))) short short8;     // 8 x bf16 bits (4 VGPRs)
typedef __attribute__((ext_vector_type(4))) float f32x4;      // MFMA accum
typedef __attribute__((ext_vector_type(4))) unsigned short ushort4v;

__device__ __forceinline__ unsigned short f2bf(float f) {
  unsigned int u = __builtin_bit_cast(unsigned int, f);
  u = u + 0x7FFFu + ((u >> 16) & 1u);   // RNE
  return (unsigned short)(u >> 16);
}
__device__ __forceinline__ float bf2f(unsigned short h) {
  unsigned int u = ((unsigned int)h) << 16;
  return __builtin_bit_cast(float, u);
}

// async global->LDS, 16B per lane; LDS dest = wave-uniform base + lane*16
__device__ __forceinline__ void gl_lds16(const unsigned short* g, unsigned short* l) {
  __builtin_amdgcn_global_load_lds(
      (const __attribute__((address_space(1))) unsigned int*)(const void*)g,
      (__attribute__((address_space(3))) unsigned int*)(void*)l, 16, 0, 0);
}

// ---------------- weight transpose+cast (+zero pad) : out[n][k] = in[k][n] ----------------
__global__ void k_transpose_cast(const float* __restrict__ in, unsigned short* __restrict__ out,
                                 int Nin, int Kin, int ldo) {
  int k = blockIdx.x * blockDim.x + threadIdx.x;
  int n = blockIdx.y;
  if (k >= ldo) return;
  float v = (n < Nin && k < Kin) ? in[(size_t)k * Nin + n] : 0.f;
  out[(size_t)n * ldo + k] = f2bf(v);
}

// ---------------- att layer 1: h = relu(t[b]*W2a[j] + b2a[j]) -> bf16 [2048x1024] ----------------
__global__ void k_att_l1(const float* __restrict__ tar, const float* __restrict__ W2a,
                         const float* __restrict__ b2a, unsigned short* __restrict__ out) {
  int id = blockIdx.x * 256 + threadIdx.x;   // 2048*1024
  int b = id >> 10, j = id & 1023;
  out[id] = f2bf(fmaxf(tar[b] * W2a[j] + b2a[j], 0.f));
}

// ---------------- v2s cast to bf16, K padded 312->320 ----------------
__global__ void k_v2s_cast(const float* __restrict__ v2s, unsigned short* __restrict__ out) {
  int id = blockIdx.x * 256 + threadIdx.x;   // 2048*320
  int r = id / 320, c = id - r * 320;
  out[id] = (c < 312) ? f2bf(v2s[(size_t)r * 312 + c]) : (unsigned short)0;
}

// ---------------- generic bf16 GEMM: C[M x N] = act(A[M x K] @ BT[N x K]^T + bias) ----------------
// 128x128 tile, BK=32, 256 thr (2x2 waves of 64x64).
// Staging: global_load_lds width=16, linear LDS dest, PRE-SWIZZLED global src so the
// LDS layout equals the slot-swizzle below (measured 0 bank conflicts in R3).
__device__ __forceinline__ int lds_off(int row, int g) {
  int slot = (g + (row >> 1)) & 3;            // spreads 8 rows over 8 bank-quads
  return row * 32 + slot * 8;                 // ushort units
}

template<bool RELU, bool OUTBF16>
__global__ __launch_bounds__(256)
void k_gemm_bt(const unsigned short* __restrict__ A, const unsigned short* __restrict__ B,
               const float* __restrict__ bias, int bias_n, int nNt, int N_store, int K,
               void* __restrict__ outp, int ldo, int remap) {
  __shared__ __align__(16) unsigned short As[128 * 32];
  __shared__ __align__(16) unsigned short Bs[128 * 32];
  int d = blockIdx.x, nwg = gridDim.x;
  int L = d;
  if (remap) { int q = nwg >> 3; L = (d & 7) * q + (d >> 3); }  // only used when nwg % 8 == 0
  int mt = L / nNt, nt = L - mt * nNt;
  size_t m0 = (size_t)mt * 128, n0 = (size_t)nt * 128;
  int tid = threadIdx.x, lane = tid & 63;
  int w = tid >> 6, wr = w >> 1, wc = w & 1;
  int sr = tid >> 2;                          // staging row (this thread covers sr and sr+64)
  // pre-swizzle: linear LDS slot s=tid&3 of row r must hold global chunk g=(s-(r>>1))&3
  int gch = ((tid & 3) - (tid >> 3)) & 3;     // identical for both row-halves (64>>1 ≡ 0 mod 4)
  const unsigned short* pA0 = A + (m0 + sr) * K + gch * 8;
  const unsigned short* pA1 = pA0 + (size_t)64 * K;
  const unsigned short* pB0 = B + (n0 + sr) * K + gch * 8;
  const unsigned short* pB1 = pB0 + (size_t)64 * K;
  unsigned short* lA0 = &As[(tid & ~63) * 8];          // + lane*16B by HW
  unsigned short* lA1 = &As[64 * 32 + (tid & ~63) * 8];
  unsigned short* lB0 = &Bs[(tid & ~63) * 8];
  unsigned short* lB1 = &Bs[64 * 32 + (tid & ~63) * 8];

  int kg = lane >> 4, l15 = lane & 15;
  int aoff = lds_off(wr * 64 + l15, kg);      // slot invariant under +16-row steps
  int boff = lds_off(wc * 64 + l15, kg);

  f32x4 acc[4][4];
  #pragma unroll
  for (int i = 0; i < 4; ++i)
    #pragma unroll
    for (int j = 0; j < 4; ++j) acc[i][j] = (f32x4)(0.f);

  for (int k0 = 0; k0 < K; k0 += 32) {
    __syncthreads();                           // prev iter's frag reads done: LDS reusable
    gl_lds16(pA0 + k0, lA0);
    gl_lds16(pA1 + k0, lA1);
    gl_lds16(pB0 + k0, lB0);
    gl_lds16(pB1 + k0, lB1);
    __syncthreads();                           // drains vmcnt(0): tile ready
    short8 af[4], bfr[4];
    #pragma unroll
    for (int mi = 0; mi < 4; ++mi) af[mi] = *(const short8*)&As[aoff + mi * 512];
    #pragma unroll
    for (int ni = 0; ni < 4; ++ni) bfr[ni] = *(const short8*)&Bs[boff + ni * 512];
    #pragma unroll
    for (int mi = 0; mi < 4; ++mi)
      #pragma unroll
      for (int ni = 0; ni < 4; ++ni)
        acc[mi][ni] = __builtin_amdgcn_mfma_f32_16x16x32_bf16(af[mi], bfr[ni], acc[mi][ni], 0, 0, 0);
  }

  #pragma unroll
  for (int ni = 0; ni < 4; ++ni) {
    int colg = (int)n0 + wc * 64 + ni * 16 + l15;
    if (colg < N_store) {
      float bs = bias ? (colg < bias_n ? bias[colg] : 0.f) : 0.f;
      #pragma unroll
      for (int mi = 0; mi < 4; ++mi) {
        #pragma unroll
        for (int r2 = 0; r2 < 4; ++r2) {
          size_t rowg = m0 + wr * 64 + mi * 16 + kg * 4 + r2;   // C/D: row=(l>>4)*4+r, col=l&15
          float v = acc[mi][ni][r2] + bs;
          if (RELU) v = fmaxf(v, 0.f);
          if (OUTBF16) ((unsigned short*)outp)[rowg * ldo + colg] = f2bf(v);
          else         ((float*)outp)[rowg * ldo + colg] = v;
        }
      }
    }
  }
}

// ------- H1c[r_local] = relu(V1[src] + A1p[arow]) -> bf16  (b1a pre-folded into A1p) -------
__global__ void k_build_h1(const float* __restrict__ V1, const float* __restrict__ A1p,
                           const int* __restrict__ idx, unsigned short* __restrict__ H1c,
                           int rbase) {
  int row = rbase + blockIdx.x;                // global row 0..133119
  int src, arow;
  if (row < 2048) { src = row; arow = row; }   // rows 0..2047 = query
  else {
    int g = row - 2048; arow = g >> 6;
    int s = idx[g];
    src = s < 0 ? 0 : (s > 2047 ? 2047 : s);
  }
  int j = threadIdx.x * 4;
  float4 v = *(const float4*)(V1 + (size_t)src * 1024 + j);
  float4 a = *(const float4*)(A1p + (size_t)arow * 1024 + j);
  ushort4v o;
  o.x = f2bf(fmaxf(v.x + a.x, 0.f));
  o.y = f2bf(fmaxf(v.y + a.y, 0.f));
  o.z = f2bf(fmaxf(v.z + a.z, 0.f));
  o.w = f2bf(fmaxf(v.w + a.w, 0.f));
  *(ushort4v*)(H1c + (size_t)blockIdx.x * 1024 + j) = o;
}

// ---------------- logits[b,k] = dot(P[b], P[2048 + b*64 + k]) / T  (P is bf16) ----------------
__global__ void k_dot(const unsigned short* __restrict__ P, float* __restrict__ out) {
  __shared__ float q[128];
  int b = blockIdx.x, t = threadIdx.x;
  if (t < 128) q[t] = bf2f(P[(size_t)b * 128 + t]);
  __syncthreads();
  int k = t >> 2, part = t & 3;
  const unsigned short* row = P + (size_t)(2048 + b * 64 + k) * 128 + part * 32;
  const float* qp = q + part * 32;
  float s = 0.f;
  #pragma unroll
  for (int j = 0; j < 32; j += 8) {
    short8 pv = *(const short8*)(row + j);
    #pragma unroll
    for (int e = 0; e < 8; ++e)
      s += bf2f((unsigned short)pv[e]) * qp[j + e];
  }
  s += __shfl_xor(s, 1);
  s += __shfl_xor(s, 2);
  if (part == 0) out[(size_t)b * 64 + k] = s * (float)(1.0 / 0.12);
}

extern "C" void kernel_launch(void* const* d_in, const int* in_sizes, int n_in,
                              void* d_out, int out_size, void* d_ws, size_t ws_size,
                              hipStream_t stream) {
  const float* v2s = (const float*)d_in[0];
  const float* tar = (const float*)d_in[1];
  const int*   sidx = (const int*)d_in[2];
  const float* W2a = (const float*)d_in[3];
  const float* b2a = (const float*)d_in[4];
  const float* W2b = (const float*)d_in[5];
  const float* b2b = (const float*)d_in[6];
  const float* W2c = (const float*)d_in[7];
  const float* b2c = (const float*)d_in[8];
  const float* W1a = (const float*)d_in[9];
  const float* b1a = (const float*)d_in[10];
  const float* W1b = (const float*)d_in[11];
  const float* b1b = (const float*)d_in[12];
  const float* W1c = (const float*)d_in[13];
  const float* b1c = (const float*)d_in[14];
  float* out = (float*)d_out;

  // ---- workspace layout: persistent region + overlay (early att-MLP temps / late chunk bufs)
  char* ws = (char*)d_ws;
  size_t off = 0;
  auto alloc = [&](size_t bytes) -> char* {
    char* p = ws + off; off += (bytes + 255) & ~(size_t)255; return p;
  };
  // persistent
  unsigned short* W1bT = (unsigned short*)alloc(2048ull * 1024 * 2);  // [2048][1024]
  unsigned short* W1cT = (unsigned short*)alloc(128ull * 2048 * 2);   // [128][2048]
  float*          V1   = (float*)alloc(2048ull * 1024 * 4);           // v2s @ W1a
  float*          A1p  = (float*)alloc(2048ull * 1024 * 4);           // att @ W1a + b1a
  unsigned short* Pb   = (unsigned short*)alloc(133120ull * 128 * 2); // bf16 projections
  // overlay
  size_t O = off;
  // early (dead before chunk loop starts)
  off = O;
  unsigned short* W1aT = (unsigned short*)alloc(1024ull * 320 * 2);   // [1024][320]  (K-pad)
  unsigned short* v2sb = (unsigned short*)alloc(2048ull * 320 * 2);
  unsigned short* attb = (unsigned short*)alloc(2048ull * 320 * 2);
  unsigned short* W2bT = (unsigned short*)alloc(2048ull * 1024 * 2);
  unsigned short* W2cT = (unsigned short*)alloc(384ull * 2048 * 2);   // [384][2048]  (N-pad)
  unsigned short* h_a  = (unsigned short*)alloc(2048ull * 1024 * 2);
  unsigned short* h2a  = (unsigned short*)alloc(2048ull * 2048 * 2);
  size_t early_end = off;

  // adaptive chunk count: largest chunk (smallest NCH) whose H1c+H2c fit ws_size.
  // deterministic (ws_size constant across calls -> identical launch sequence).
  const int cands[5] = {1, 2, 4, 8, 16};
  int NCH = -1, R = 0;
  size_t needed = 0;
  for (int ci = 0; ci < 5; ++ci) {
    int c = cands[ci];
    size_t Rr = 133120ull / c;
    size_t late = O + (((Rr * 1024 * 2) + 255) & ~(size_t)255)
                    + (((Rr * 2048 * 2) + 255) & ~(size_t)255);
    size_t need = late > early_end ? late : early_end;
    if (need <= ws_size) { NCH = c; R = (int)Rr; needed = need; break; }
  }
  fprintf(stderr, "[kernel_launch] ws_size=%zu NCH=%d needed=%zu\n", ws_size, NCH, needed);
  if (NCH < 0) {   // diagnostic fallback: zero output, no OOB write
    hipMemsetAsync(d_out, 0, (size_t)out_size * 4, stream);
    return;
  }
  off = O;
  unsigned short* H1c = (unsigned short*)alloc((size_t)R * 1024 * 2);
  unsigned short* H2c = (unsigned short*)alloc((size_t)R * 2048 * 2);

  dim3 blk(256);
  // weight prep
  k_transpose_cast<<<dim3(4, 2048), blk, 0, stream>>>(W2b, W2bT, 2048, 1024, 1024);
  k_transpose_cast<<<dim3(8, 384),  blk, 0, stream>>>(W2c, W2cT, 312, 2048, 2048);
  k_transpose_cast<<<dim3(2, 1024), blk, 0, stream>>>(W1a, W1aT, 1024, 312, 320);
  k_transpose_cast<<<dim3(4, 2048), blk, 0, stream>>>(W1b, W1bT, 2048, 1024, 1024);
  k_transpose_cast<<<dim3(8, 128),  blk, 0, stream>>>(W1c, W1cT, 128, 2048, 2048);
  k_att_l1<<<8192, blk, 0, stream>>>(tar, W2a, b2a, h_a);
  k_v2s_cast<<<2560, blk, 0, stream>>>(v2s, v2sb);
  // att MLP: h2a = relu(h_a @ W2b + b2b); attb = relu(h2a @ W2c + b2c) (cols 312..319 = 0)
  k_gemm_bt<true,  true ><<<256, blk, 0, stream>>>(h_a,  W2bT, b2b, 2048, 16, 2048, 1024, h2a,  2048, 1);
  k_gemm_bt<true,  true ><<<48,  blk, 0, stream>>>(h2a,  W2cT, b2c, 312,  3,  320,  2048, attb, 320,  1);
  // layer-1 factored: V1 = v2s@W1a (no bias); A1p = att@W1a + b1a  (f32 out, no act)
  k_gemm_bt<false, false><<<128, blk, 0, stream>>>(v2sb, W1aT, nullptr, 0,  8, 1024, 320, V1,  1024, 1);
  k_gemm_bt<false, false><<<128, blk, 0, stream>>>(attb, W1aT, b1a, 1024,  8, 1024, 320, A1p, 1024, 1);
  // chunked: build H1 -> layer2 -> layer3
  for (int c = 0; c < NCH; ++c) {
    int rbase = c * R;
    k_build_h1<<<R, blk, 0, stream>>>(V1, A1p, sidx, H1c, rbase);
    k_gemm_bt<true, true><<<(R / 128) * 16, blk, 0, stream>>>(H1c, W1bT, b1b, 2048, 16, 2048, 1024, H2c, 2048, 1);
    k_gemm_bt<true, true><<<(R / 128), blk, 0, stream>>>(H2c, W1cT, b1c, 128, 1, 128, 2048,
                                                          Pb + (size_t)rbase * 128, 128, 0);
  }
  // logits
  k_dot<<<2048, blk, 0, stream>>>(Pb, out);
}

// Round 5
// 1165.761 us; speedup vs baseline: 1.4128x; 1.0065x over previous
//
#include <hip/hip_runtime.h>
#include <stdio.h>
#include <stdint.h>

typedef __attribute__((ext_vector_type(8))) short short8;     // 8 x bf16 bits (4 VGPRs)
typedef __attribute__((ext_vector_type(4))) float f32x4;      // MFMA accum
typedef __attribute__((ext_vector_type(4))) unsigned short ushort4v;

__device__ __forceinline__ unsigned short f2bf(float f) {
  unsigned int u = __builtin_bit_cast(unsigned int, f);
  u = u + 0x7FFFu + ((u >> 16) & 1u);   // RNE
  return (unsigned short)(u >> 16);
}
__device__ __forceinline__ float bf2f(unsigned short h) {
  unsigned int u = ((unsigned int)h) << 16;
  return __builtin_bit_cast(float, u);
}

// async global->LDS, 16B per lane; LDS dest = wave-uniform base + lane*16
__device__ __forceinline__ void gl_lds16(const unsigned short* g, unsigned short* l) {
  __builtin_amdgcn_global_load_lds(
      (const __attribute__((address_space(1))) unsigned int*)(const void*)g,
      (__attribute__((address_space(3))) unsigned int*)(void*)l, 16, 0, 0);
}

// LDS slot swizzle (proven 0 bank conflicts in R3/R4): slot s of row r holds k-chunk (s-(r>>1))&3
__device__ __forceinline__ int lds_off(int row, int g) {
  int slot = (g + (row >> 1)) & 3;
  return row * 32 + slot * 8;                 // ushort units, ld=32
}

// ---------------- weight transpose+cast (+zero pad) : out[n][k] = in[k][n] ----------------
__global__ void k_transpose_cast(const float* __restrict__ in, unsigned short* __restrict__ out,
                                 int Nin, int Kin, int ldo) {
  int k = blockIdx.x * blockDim.x + threadIdx.x;
  int n = blockIdx.y;
  if (k >= ldo) return;
  float v = (n < Nin && k < Kin) ? in[(size_t)k * Nin + n] : 0.f;
  out[(size_t)n * ldo + k] = f2bf(v);
}

// ---------------- att layer 1: h = relu(t[b]*W2a[j] + b2a[j]) -> bf16 [2048x1024] ----------------
__global__ void k_att_l1(const float* __restrict__ tar, const float* __restrict__ W2a,
                         const float* __restrict__ b2a, unsigned short* __restrict__ out) {
  int id = blockIdx.x * 256 + threadIdx.x;   // 2048*1024
  int b = id >> 10, j = id & 1023;
  out[id] = f2bf(fmaxf(tar[b] * W2a[j] + b2a[j], 0.f));
}

// ---------------- v2s cast to bf16, K padded 312->320 ----------------
__global__ void k_v2s_cast(const float* __restrict__ v2s, unsigned short* __restrict__ out) {
  int id = blockIdx.x * 256 + threadIdx.x;   // 2048*320
  int r = id / 320, c = id - r * 320;
  out[id] = (c < 312) ? f2bf(v2s[(size_t)r * 312 + c]) : (unsigned short)0;
}

// ============ 256x256 tile GEMM: C = relu(A[M x K] @ BT[N x K]^T + bias) -> bf16 ============
// BK=32, 512 thr = 8 waves (2M x 4N), per-wave out 128x64 (acc[8][4]).
// 3 LDS buffers, 2-ahead staging via global_load_lds, counted vmcnt(4) BEFORE the single
// per-step barrier (so barrier propagates every wave's landing guarantee). T5 setprio on MFMA.
// Liveness: step t reads buf[t%3]; stage(t+2)->buf[(t+2)%3] == buffer of tile t-1, fully
// retired at step t-1's barrier, and the stage is issued after that barrier. Race-free.
__global__ __launch_bounds__(512, 2)
void k_gemm256(const unsigned short* __restrict__ A, const unsigned short* __restrict__ B,
               const float* __restrict__ bias, int nNt, int K,
               unsigned short* __restrict__ outp, int ldo) {
  __shared__ __align__(16) unsigned short sm[3 * 16384];   // buf b: A @ b*16384, B @ +8192 (96 KiB)
  int d = blockIdx.x, nwg = gridDim.x;
  int q = nwg >> 3;                            // nwg % 8 == 0 guaranteed by launcher
  int L = (d & 7) * q + (d >> 3);              // XCD-contiguous chunks
  int mt = L / nNt, nt = L - mt * nNt;
  size_t m0 = (size_t)mt * 256, n0 = (size_t)nt * 256;
  int tid = threadIdx.x, lane = tid & 63;
  int w = tid >> 6, wr = w >> 2, wc = w & 3;
  // staging: round r covers rows r*128+[0..127]; thread -> row (tid>>2), swizzled k-chunk
  int r0 = tid >> 2;
  int gch = ((tid & 3) - (tid >> 3)) & 3;      // pre-swizzled global chunk (rule #21)
  const unsigned short* Asrc0 = A + (m0 + r0) * K + gch * 8;
  const unsigned short* Asrc1 = A + (m0 + r0 + 128) * K + gch * 8;
  const unsigned short* Bsrc0 = B + (n0 + r0) * K + gch * 8;
  const unsigned short* Bsrc1 = B + (n0 + r0 + 128) * K + gch * 8;
  int ldst0 = w * 512;                         // wave-uniform LDS dest (ushorts); HW adds lane*16B
  int ldst1 = 4096 + w * 512;

#define STAGE(t_, b_) do {                                              \
    int k0_ = (t_) * 32;                                                \
    unsigned short* Ab_ = &sm[(b_) * 16384];                            \
    unsigned short* Bb_ = &sm[(b_) * 16384 + 8192];                     \
    gl_lds16(Asrc0 + k0_, Ab_ + ldst0);                                 \
    gl_lds16(Asrc1 + k0_, Ab_ + ldst1);                                 \
    gl_lds16(Bsrc0 + k0_, Bb_ + ldst0);                                 \
    gl_lds16(Bsrc1 + k0_, Bb_ + ldst1);                                 \
  } while (0)

  int kg = lane >> 4, l15 = lane & 15;
  int aoff = lds_off(wr * 128 + l15, kg);      // slot invariant under +16-row steps
  int boff = lds_off(wc * 64 + l15, kg);

  f32x4 acc[8][4];
  #pragma unroll
  for (int i = 0; i < 8; ++i)
    #pragma unroll
    for (int j = 0; j < 4; ++j) acc[i][j] = (f32x4)(0.f);

  const int NT = K >> 5;                       // K % 32 == 0, NT >= 2
  STAGE(0, 0);
  STAGE(1, 1);
  asm volatile("s_waitcnt vmcnt(4)" ::: "memory");   // tile 0 landed (mine); barrier globalizes
  __syncthreads();

  for (int t = 0; t < NT; ++t) {
    int cur = t % 3;
    if (t + 2 < NT) STAGE(t + 2, (t + 2) % 3);       // overlaps compute; 2-step slack
    const unsigned short* Ab = &sm[cur * 16384];
    const unsigned short* Bb = &sm[cur * 16384 + 8192];
    short8 af[8], bfv[4];
    #pragma unroll
    for (int mi = 0; mi < 8; ++mi) af[mi] = *(const short8*)&Ab[aoff + mi * 512];
    #pragma unroll
    for (int ni = 0; ni < 4; ++ni) bfv[ni] = *(const short8*)&Bb[boff + ni * 512];
    __builtin_amdgcn_s_setprio(1);
    #pragma unroll
    for (int mi = 0; mi < 8; ++mi)
      #pragma unroll
      for (int ni = 0; ni < 4; ++ni)
        acc[mi][ni] = __builtin_amdgcn_mfma_f32_16x16x32_bf16(af[mi], bfv[ni], acc[mi][ni], 0, 0, 0);
    __builtin_amdgcn_s_setprio(0);
    if (t + 1 < NT) {
      if (t + 2 < NT) asm volatile("s_waitcnt vmcnt(4)" ::: "memory");  // t+1 landed, t+2 in flight
      else            asm volatile("s_waitcnt vmcnt(0)" ::: "memory");  // drain last tile
      __syncthreads();                         // globalizes landing + retires buf[cur]
    }
  }
#undef STAGE

  #pragma unroll
  for (int ni = 0; ni < 4; ++ni) {
    int colg = (int)n0 + wc * 64 + ni * 16 + l15;
    float bs = bias[colg];
    #pragma unroll
    for (int mi = 0; mi < 8; ++mi) {
      #pragma unroll
      for (int r2 = 0; r2 < 4; ++r2) {
        size_t rowg = m0 + wr * 128 + mi * 16 + kg * 4 + r2;   // C/D: row=(l>>4)*4+r, col=l&15
        outp[rowg * ldo + colg] = f2bf(fmaxf(acc[mi][ni][r2] + bs, 0.f));
      }
    }
  }
}

// ---------------- generic 128x128 bf16 GEMM (unchanged, R4-verified) ----------------
template<bool RELU, bool OUTBF16>
__global__ __launch_bounds__(256)
void k_gemm_bt(const unsigned short* __restrict__ A, const unsigned short* __restrict__ B,
               const float* __restrict__ bias, int bias_n, int nNt, int N_store, int K,
               void* __restrict__ outp, int ldo, int remap) {
  __shared__ __align__(16) unsigned short As[128 * 32];
  __shared__ __align__(16) unsigned short Bs[128 * 32];
  int d = blockIdx.x, nwg = gridDim.x;
  int L = d;
  if (remap) { int q = nwg >> 3; L = (d & 7) * q + (d >> 3); }  // only used when nwg % 8 == 0
  int mt = L / nNt, nt = L - mt * nNt;
  size_t m0 = (size_t)mt * 128, n0 = (size_t)nt * 128;
  int tid = threadIdx.x, lane = tid & 63;
  int w = tid >> 6, wr = w >> 1, wc = w & 1;
  int sr = tid >> 2;
  int gch = ((tid & 3) - (tid >> 3)) & 3;
  const unsigned short* pA0 = A + (m0 + sr) * K + gch * 8;
  const unsigned short* pA1 = pA0 + (size_t)64 * K;
  const unsigned short* pB0 = B + (n0 + sr) * K + gch * 8;
  const unsigned short* pB1 = pB0 + (size_t)64 * K;
  unsigned short* lA0 = &As[(tid & ~63) * 8];
  unsigned short* lA1 = &As[64 * 32 + (tid & ~63) * 8];
  unsigned short* lB0 = &Bs[(tid & ~63) * 8];
  unsigned short* lB1 = &Bs[64 * 32 + (tid & ~63) * 8];

  int kg = lane >> 4, l15 = lane & 15;
  int aoff = lds_off(wr * 64 + l15, kg);
  int boff = lds_off(wc * 64 + l15, kg);

  f32x4 acc[4][4];
  #pragma unroll
  for (int i = 0; i < 4; ++i)
    #pragma unroll
    for (int j = 0; j < 4; ++j) acc[i][j] = (f32x4)(0.f);

  for (int k0 = 0; k0 < K; k0 += 32) {
    __syncthreads();
    gl_lds16(pA0 + k0, lA0);
    gl_lds16(pA1 + k0, lA1);
    gl_lds16(pB0 + k0, lB0);
    gl_lds16(pB1 + k0, lB1);
    __syncthreads();
    short8 af[4], bfr[4];
    #pragma unroll
    for (int mi = 0; mi < 4; ++mi) af[mi] = *(const short8*)&As[aoff + mi * 512];
    #pragma unroll
    for (int ni = 0; ni < 4; ++ni) bfr[ni] = *(const short8*)&Bs[boff + ni * 512];
    #pragma unroll
    for (int mi = 0; mi < 4; ++mi)
      #pragma unroll
      for (int ni = 0; ni < 4; ++ni)
        acc[mi][ni] = __builtin_amdgcn_mfma_f32_16x16x32_bf16(af[mi], bfr[ni], acc[mi][ni], 0, 0, 0);
  }

  #pragma unroll
  for (int ni = 0; ni < 4; ++ni) {
    int colg = (int)n0 + wc * 64 + ni * 16 + l15;
    if (colg < N_store) {
      float bs = bias ? (colg < bias_n ? bias[colg] : 0.f) : 0.f;
      #pragma unroll
      for (int mi = 0; mi < 4; ++mi) {
        #pragma unroll
        for (int r2 = 0; r2 < 4; ++r2) {
          size_t rowg = m0 + wr * 64 + mi * 16 + kg * 4 + r2;
          float v = acc[mi][ni][r2] + bs;
          if (RELU) v = fmaxf(v, 0.f);
          if (OUTBF16) ((unsigned short*)outp)[rowg * ldo + colg] = f2bf(v);
          else         ((float*)outp)[rowg * ldo + colg] = v;
        }
      }
    }
  }
}

// ------- H1c[r_local] = relu(V1[src] + A1p[arow]) -> bf16  (b1a pre-folded into A1p) -------
__global__ void k_build_h1(const float* __restrict__ V1, const float* __restrict__ A1p,
                           const int* __restrict__ idx, unsigned short* __restrict__ H1c,
                           int rbase) {
  int row = rbase + blockIdx.x;                // global row 0..133119
  int src, arow;
  if (row < 2048) { src = row; arow = row; }   // rows 0..2047 = query
  else {
    int g = row - 2048; arow = g >> 6;
    int s = idx[g];
    src = s < 0 ? 0 : (s > 2047 ? 2047 : s);
  }
  int j = threadIdx.x * 4;
  float4 v = *(const float4*)(V1 + (size_t)src * 1024 + j);
  float4 a = *(const float4*)(A1p + (size_t)arow * 1024 + j);
  ushort4v o;
  o.x = f2bf(fmaxf(v.x + a.x, 0.f));
  o.y = f2bf(fmaxf(v.y + a.y, 0.f));
  o.z = f2bf(fmaxf(v.z + a.z, 0.f));
  o.w = f2bf(fmaxf(v.w + a.w, 0.f));
  *(ushort4v*)(H1c + (size_t)blockIdx.x * 1024 + j) = o;
}

// ---------------- logits[b,k] = dot(P[b], P[2048 + b*64 + k]) / T  (P is bf16) ----------------
__global__ void k_dot(const unsigned short* __restrict__ P, float* __restrict__ out) {
  __shared__ float q[128];
  int b = blockIdx.x, t = threadIdx.x;
  if (t < 128) q[t] = bf2f(P[(size_t)b * 128 + t]);
  __syncthreads();
  int k = t >> 2, part = t & 3;
  const unsigned short* row = P + (size_t)(2048 + b * 64 + k) * 128 + part * 32;
  const float* qp = q + part * 32;
  float s = 0.f;
  #pragma unroll
  for (int j = 0; j < 32; j += 8) {
    short8 pv = *(const short8*)(row + j);
    #pragma unroll
    for (int e = 0; e < 8; ++e)
      s += bf2f((unsigned short)pv[e]) * qp[j + e];
  }
  s += __shfl_xor(s, 1);
  s += __shfl_xor(s, 2);
  if (part == 0) out[(size_t)b * 64 + k] = s * (float)(1.0 / 0.12);
}

extern "C" void kernel_launch(void* const* d_in, const int* in_sizes, int n_in,
                              void* d_out, int out_size, void* d_ws, size_t ws_size,
                              hipStream_t stream) {
  const float* v2s = (const float*)d_in[0];
  const float* tar = (const float*)d_in[1];
  const int*   sidx = (const int*)d_in[2];
  const float* W2a = (const float*)d_in[3];
  const float* b2a = (const float*)d_in[4];
  const float* W2b = (const float*)d_in[5];
  const float* b2b = (const float*)d_in[6];
  const float* W2c = (const float*)d_in[7];
  const float* b2c = (const float*)d_in[8];
  const float* W1a = (const float*)d_in[9];
  const float* b1a = (const float*)d_in[10];
  const float* W1b = (const float*)d_in[11];
  const float* b1b = (const float*)d_in[12];
  const float* W1c = (const float*)d_in[13];
  const float* b1c = (const float*)d_in[14];
  float* out = (float*)d_out;

  // ---- workspace layout: persistent region + overlay (early att-MLP temps / late chunk bufs)
  char* ws = (char*)d_ws;
  size_t off = 0;
  auto alloc = [&](size_t bytes) -> char* {
    char* p = ws + off; off += (bytes + 255) & ~(size_t)255; return p;
  };
  // persistent
  unsigned short* W1bT = (unsigned short*)alloc(2048ull * 1024 * 2);  // [2048][1024]
  unsigned short* W1cT = (unsigned short*)alloc(128ull * 2048 * 2);   // [128][2048]
  float*          V1   = (float*)alloc(2048ull * 1024 * 4);           // v2s @ W1a
  float*          A1p  = (float*)alloc(2048ull * 1024 * 4);           // att @ W1a + b1a
  unsigned short* Pb   = (unsigned short*)alloc(133120ull * 128 * 2); // bf16 projections
  // overlay
  size_t O = off;
  // early (dead before chunk loop starts)
  off = O;
  unsigned short* W1aT = (unsigned short*)alloc(1024ull * 320 * 2);   // [1024][320]  (K-pad)
  unsigned short* v2sb = (unsigned short*)alloc(2048ull * 320 * 2);
  unsigned short* attb = (unsigned short*)alloc(2048ull * 320 * 2);
  unsigned short* W2bT = (unsigned short*)alloc(2048ull * 1024 * 2);
  unsigned short* W2cT = (unsigned short*)alloc(384ull * 2048 * 2);   // [384][2048]  (N-pad)
  unsigned short* h_a  = (unsigned short*)alloc(2048ull * 1024 * 2);
  unsigned short* h2a  = (unsigned short*)alloc(2048ull * 2048 * 2);
  size_t early_end = off;

  // adaptive chunk count: prefer chunks with R % 256 == 0 (256-tile GEMM); NCH=16 fallback.
  const int cands[4] = {1, 2, 4, 8};
  int NCH = -1, R = 0;
  for (int ci = 0; ci < 4; ++ci) {
    int c = cands[ci];
    size_t Rr = 133120ull / c;
    size_t late = O + (((Rr * 1024 * 2) + 255) & ~(size_t)255)
                    + (((Rr * 2048 * 2) + 255) & ~(size_t)255);
    size_t need = late > early_end ? late : early_end;
    if (need <= ws_size) { NCH = c; R = (int)Rr; break; }
  }
  int use256 = (NCH > 0);
  if (NCH < 0) {
    size_t Rr = 133120ull / 16;
    size_t late = O + (((Rr * 1024 * 2) + 255) & ~(size_t)255)
                    + (((Rr * 2048 * 2) + 255) & ~(size_t)255);
    size_t need = late > early_end ? late : early_end;
    if (need <= ws_size) { NCH = 16; R = (int)Rr; }
  }
  fprintf(stderr, "[kernel_launch] ws_size=%zu NCH=%d use256=%d\n", ws_size, NCH, use256);
  if (NCH < 0) {   // diagnostic fallback: zero output, no OOB write
    hipMemsetAsync(d_out, 0, (size_t)out_size * 4, stream);
    return;
  }
  off = O;
  unsigned short* H1c = (unsigned short*)alloc((size_t)R * 1024 * 2);
  unsigned short* H2c = (unsigned short*)alloc((size_t)R * 2048 * 2);

  dim3 blk(256);
  // weight prep
  k_transpose_cast<<<dim3(4, 2048), blk, 0, stream>>>(W2b, W2bT, 2048, 1024, 1024);
  k_transpose_cast<<<dim3(8, 384),  blk, 0, stream>>>(W2c, W2cT, 312, 2048, 2048);
  k_transpose_cast<<<dim3(2, 1024), blk, 0, stream>>>(W1a, W1aT, 1024, 312, 320);
  k_transpose_cast<<<dim3(4, 2048), blk, 0, stream>>>(W1b, W1bT, 2048, 1024, 1024);
  k_transpose_cast<<<dim3(8, 128),  blk, 0, stream>>>(W1c, W1cT, 128, 2048, 2048);
  k_att_l1<<<8192, blk, 0, stream>>>(tar, W2a, b2a, h_a);
  k_v2s_cast<<<2560, blk, 0, stream>>>(v2s, v2sb);
  // att MLP: h2a = relu(h_a @ W2b + b2b); attb = relu(h2a @ W2c + b2c) (cols 312..319 = 0)
  k_gemm_bt<true,  true ><<<256, blk, 0, stream>>>(h_a,  W2bT, b2b, 2048, 16, 2048, 1024, h2a,  2048, 1);
  k_gemm_bt<true,  true ><<<48,  blk, 0, stream>>>(h2a,  W2cT, b2c, 312,  3,  320,  2048, attb, 320,  1);
  // layer-1 factored: V1 = v2s@W1a (no bias); A1p = att@W1a + b1a  (f32 out, no act)
  k_gemm_bt<false, false><<<128, blk, 0, stream>>>(v2sb, W1aT, nullptr, 0,  8, 1024, 320, V1,  1024, 1);
  k_gemm_bt<false, false><<<128, blk, 0, stream>>>(attb, W1aT, b1a, 1024,  8, 1024, 320, A1p, 1024, 1);
  // chunked: build H1 -> layer2 (256-tile pipelined) -> layer3
  for (int c = 0; c < NCH; ++c) {
    int rbase = c * R;
    k_build_h1<<<R, blk, 0, stream>>>(V1, A1p, sidx, H1c, rbase);
    if (use256)
      k_gemm256<<<(R / 256) * 8, dim3(512), 0, stream>>>(H1c, W1bT, b1b, 8, 1024, H2c, 2048);
    else
      k_gemm_bt<true, true><<<(R / 128) * 16, blk, 0, stream>>>(H1c, W1bT, b1b, 2048, 16, 2048, 1024, H2c, 2048, 1);
    k_gemm_bt<true, true><<<(R / 128), blk, 0, stream>>>(H2c, W1cT, b1c, 128, 1, 128, 2048,
                                                          Pb + (size_t)rbase * 128, 128, 0);
  }
  // logits
  k_dot<<<2048, blk, 0, stream>>>(Pb, out);
}

// Round 6
// 1142.947 us; speedup vs baseline: 1.4410x; 1.0200x over previous
//
#include <hip/hip_runtime.h>
#include <stdio.h>
#include <stdint.h>

typedef __attribute__((ext_vector_type(8))) short short8;     // 8 x bf16 bits (4 VGPRs)
typedef __attribute__((ext_vector_type(4))) float f32x4;      // MFMA accum
typedef __attribute__((ext_vector_type(4))) unsigned short ushort4v;

__device__ __forceinline__ unsigned short f2bf(float f) {
  unsigned int u = __builtin_bit_cast(unsigned int, f);
  u = u + 0x7FFFu + ((u >> 16) & 1u);   // RNE
  return (unsigned short)(u >> 16);
}
__device__ __forceinline__ float bf2f(unsigned short h) {
  unsigned int u = ((unsigned int)h) << 16;
  return __builtin_bit_cast(float, u);
}

// async global->LDS, 16B per lane; LDS dest = wave-uniform base + lane*16
__device__ __forceinline__ void gl_lds16(const unsigned short* g, unsigned short* l) {
  __builtin_amdgcn_global_load_lds(
      (const __attribute__((address_space(1))) unsigned int*)(const void*)g,
      (__attribute__((address_space(3))) unsigned int*)(void*)l, 16, 0, 0);
}

#define RAW_BAR()  asm volatile("s_barrier" ::: "memory")
#define LGKM0()    asm volatile("s_waitcnt lgkmcnt(0)" ::: "memory")
#define VMCNT(n_)  asm volatile("s_waitcnt vmcnt(" #n_ ")" ::: "memory")

// ---------------- weight transpose+cast (+zero pad) : out[n][k] = in[k][n] ----------------
__global__ void k_transpose_cast(const float* __restrict__ in, unsigned short* __restrict__ out,
                                 int Nin, int Kin, int ldo) {
  int k = blockIdx.x * blockDim.x + threadIdx.x;
  int n = blockIdx.y;
  if (k >= ldo) return;
  float v = (n < Nin && k < Kin) ? in[(size_t)k * Nin + n] : 0.f;
  out[(size_t)n * ldo + k] = f2bf(v);
}

// ---------------- att layer 1: h = relu(t[b]*W2a[j] + b2a[j]) -> bf16 [2048x1024] ----------------
__global__ void k_att_l1(const float* __restrict__ tar, const float* __restrict__ W2a,
                         const float* __restrict__ b2a, unsigned short* __restrict__ out) {
  int id = blockIdx.x * 256 + threadIdx.x;   // 2048*1024
  int b = id >> 10, j = id & 1023;
  out[id] = f2bf(fmaxf(tar[b] * W2a[j] + b2a[j], 0.f));
}

// ---------------- v2s cast to bf16, K padded 312->320 ----------------
__global__ void k_v2s_cast(const float* __restrict__ v2s, unsigned short* __restrict__ out) {
  int id = blockIdx.x * 256 + threadIdx.x;   // 2048*320
  int r = id / 320, c = id - r * 320;
  out[id] = (c < 312) ? f2bf(v2s[(size_t)r * 312 + c]) : (unsigned short)0;
}

// ======== 256x256 8-phase GEMM (T3+T4+T5): C = relu(A[M x K] @ BT[N x K]^T + bias) ========
// BK=64, 512 thr = 8 waves (2M x 4N), per-wave C 128x64 (acc[8][4]).
// LDS 128KB: dbuf d at d*32768 ushorts; A[256][64] at +0, B(T)[256][64] at +16384.
// Swizzle: LDS slot s (16B) of row r holds k-chunk (s-r)&7; inverse on global src (rule #21).
// Per K-tile u (dbuf d=u&1), 4 phases x 16 MFMA:
//   P0: read A(mi0-3,ks0-1)+B(ni0-1,ks0-1); stage A-half0(u+1)->d^1; BAR;lgkm0; MFMA mi0-3 x ni0-1
//   P1: read B(ni2-3);                      stage A-half1(u+1)->d^1; BAR;lgkm0; MFMA mi0-3 x ni2-3
//   P2: read A(mi4-7);                      stage B-half0(u+2)->d  ; BAR;lgkm0; MFMA mi4-7 x ni0-1
//   P3: (no reads)                          stage B-half1(u+2)->d  ;           MFMA mi4-7 x ni2-3
//       vmcnt(4) [vmcnt(0) at u=NT-2]; BAR
// Liveness: A-halves of dbuf d^1 last read at P2(u-1) (< P0(u) stage); B-halves of dbuf d last
// read at P1(u) (< P2(u) stage). vmcnt(4) leaves only {B0,B1(u+2)} in flight => tile u+1 landed.
__global__ __launch_bounds__(512, 2)
void k_gemm256p8(const unsigned short* __restrict__ A, const unsigned short* __restrict__ B,
                 const float* __restrict__ bias, int nNt, int K,
                 unsigned short* __restrict__ outp, int ldo) {
  __shared__ __align__(16) unsigned short sm[65536];   // 128 KiB
  int d0 = blockIdx.x, nwg = gridDim.x;
  int q = nwg >> 3;                            // nwg % 8 == 0 guaranteed by launcher
  int L = (d0 & 7) * q + (d0 >> 3);            // XCD-contiguous chunks
  int mt = L / nNt, nt = L - mt * nNt;
  size_t m0 = (size_t)mt * 256, n0 = (size_t)nt * 256;
  int tid = threadIdx.x, lane = tid & 63;
  int w = tid >> 6, wr = w >> 2, wc = w & 3;

  // staging: thread -> row srow (64 rows/G-load), slot tid&7; source chunk = inverse swizzle
  int srow = tid >> 3;
  int gch = ((tid & 7) - srow) & 7;            // (h*128+g*64) = 0 mod 8 -> same for all stages
  const unsigned short* Asrc = A + (m0 + srow) * K + gch * 8;
  const unsigned short* Bsrc = B + (n0 + srow) * K + gch * 8;
  int sdst = w * 512;                          // wave-uniform; HW adds lane*16B

#define STAGE_A(u_, h_) do { int db_ = ((u_) & 1) * 32768, ko_ = (u_) * 64;          \
    gl_lds16(Asrc + ((h_) * 128 + 0 ) * K + ko_, sm + db_ + (h_) * 8192 + 0    + sdst); \
    gl_lds16(Asrc + ((h_) * 128 + 64) * K + ko_, sm + db_ + (h_) * 8192 + 4096 + sdst); \
  } while (0)
#define STAGE_B(u_, h_) do { int db_ = ((u_) & 1) * 32768 + 16384, ko_ = (u_) * 64;  \
    gl_lds16(Bsrc + ((h_) * 128 + 0 ) * K + ko_, sm + db_ + (h_) * 8192 + 0    + sdst); \
    gl_lds16(Bsrc + ((h_) * 128 + 64) * K + ko_, sm + db_ + (h_) * 8192 + 4096 + sdst); \
  } while (0)

  // frag-read offsets (ushorts): row*64 + slot*8, slot = (ks*4 + kg + row)&7, invariant in mi*16
  int kg = lane >> 4, l15 = lane & 15;
  int CA = wr * 128 + l15;
  int CB = wc * 64 + l15;
  int aoffs[2] = { CA * 64 + ((kg + CA) & 7) * 8, CA * 64 + ((kg + CA + 4) & 7) * 8 };
  int boffs[2] = { CB * 64 + ((kg + CB) & 7) * 8, CB * 64 + ((kg + CB + 4) & 7) * 8 };

  f32x4 acc[8][4];
  #pragma unroll
  for (int i = 0; i < 8; ++i)
    #pragma unroll
    for (int j = 0; j < 4; ++j) acc[i][j] = (f32x4)(0.f);

  const int NT = K >> 6;                       // K=1024 -> 16 K-tiles

  // prologue: tile 0 fully + B-halves of tile 1 (slots P2(-1)/P3(-1) of the steady schedule)
  STAGE_A(0, 0); STAGE_A(0, 1); STAGE_B(0, 0); STAGE_B(0, 1);
  STAGE_B(1, 0); STAGE_B(1, 1);
  VMCNT(4);                                    // tile 0's 8 loads landed; B(1) may be in flight
  RAW_BAR();

  short8 af[4][2], bfv[4][2];
  for (int u = 0; u < NT; ++u) {
    const unsigned short* Ab = sm + (u & 1) * 32768;
    const unsigned short* Bb = Ab + 16384;
    // ---- P0
    #pragma unroll
    for (int mi = 0; mi < 4; ++mi)
      #pragma unroll
      for (int ks = 0; ks < 2; ++ks) af[mi][ks] = *(const short8*)&Ab[aoffs[ks] + mi * 1024];
    #pragma unroll
    for (int ni = 0; ni < 2; ++ni)
      #pragma unroll
      for (int ks = 0; ks < 2; ++ks) bfv[ni][ks] = *(const short8*)&Bb[boffs[ks] + ni * 1024];
    if (u + 1 < NT) STAGE_A(u + 1, 0);
    RAW_BAR(); LGKM0();
    __builtin_amdgcn_s_setprio(1);
    #pragma unroll
    for (int mi = 0; mi < 4; ++mi)
      #pragma unroll
      for (int ni = 0; ni < 2; ++ni)
        #pragma unroll
        for (int ks = 0; ks < 2; ++ks)
          acc[mi][ni] = __builtin_amdgcn_mfma_f32_16x16x32_bf16(af[mi][ks], bfv[ni][ks], acc[mi][ni], 0, 0, 0);
    __builtin_amdgcn_s_setprio(0);
    RAW_BAR();
    // ---- P1
    #pragma unroll
    for (int ni = 2; ni < 4; ++ni)
      #pragma unroll
      for (int ks = 0; ks < 2; ++ks) bfv[ni][ks] = *(const short8*)&Bb[boffs[ks] + ni * 1024];
    if (u + 1 < NT) STAGE_A(u + 1, 1);
    RAW_BAR(); LGKM0();
    __builtin_amdgcn_s_setprio(1);
    #pragma unroll
    for (int mi = 0; mi < 4; ++mi)
      #pragma unroll
      for (int ni = 2; ni < 4; ++ni)
        #pragma unroll
        for (int ks = 0; ks < 2; ++ks)
          acc[mi][ni] = __builtin_amdgcn_mfma_f32_16x16x32_bf16(af[mi][ks], bfv[ni][ks], acc[mi][ni], 0, 0, 0);
    __builtin_amdgcn_s_setprio(0);
    RAW_BAR();
    // ---- P2
    #pragma unroll
    for (int mi = 0; mi < 4; ++mi)
      #pragma unroll
      for (int ks = 0; ks < 2; ++ks) af[mi][ks] = *(const short8*)&Ab[aoffs[ks] + (mi + 4) * 1024];
    if (u + 2 < NT) STAGE_B(u + 2, 0);
    RAW_BAR(); LGKM0();
    __builtin_amdgcn_s_setprio(1);
    #pragma unroll
    for (int mi = 0; mi < 4; ++mi)
      #pragma unroll
      for (int ni = 0; ni < 2; ++ni)
        #pragma unroll
        for (int ks = 0; ks < 2; ++ks)
          acc[mi + 4][ni] = __builtin_amdgcn_mfma_f32_16x16x32_bf16(af[mi][ks], bfv[ni][ks], acc[mi + 4][ni], 0, 0, 0);
    __builtin_amdgcn_s_setprio(0);
    RAW_BAR();
    // ---- P3
    if (u + 2 < NT) STAGE_B(u + 2, 1);
    __builtin_amdgcn_s_setprio(1);
    #pragma unroll
    for (int mi = 0; mi < 4; ++mi)
      #pragma unroll
      for (int ni = 2; ni < 4; ++ni)
        #pragma unroll
        for (int ks = 0; ks < 2; ++ks)
          acc[mi + 4][ni] = __builtin_amdgcn_mfma_f32_16x16x32_bf16(af[mi][ks], bfv[ni][ks], acc[mi + 4][ni], 0, 0, 0);
    __builtin_amdgcn_s_setprio(0);
    if (u + 1 < NT) {
      if (u + 2 < NT) { VMCNT(4); }            // tile u+1 landed; B(u+2) stays in flight
      else            { VMCNT(0); }            // last prefetch boundary: drain
      RAW_BAR();
    }
  }
#undef STAGE_A
#undef STAGE_B

  #pragma unroll
  for (int ni = 0; ni < 4; ++ni) {
    int colg = (int)n0 + wc * 64 + ni * 16 + l15;
    float bs = bias[colg];
    #pragma unroll
    for (int mi = 0; mi < 8; ++mi) {
      #pragma unroll
      for (int r2 = 0; r2 < 4; ++r2) {
        size_t rowg = m0 + wr * 128 + mi * 16 + kg * 4 + r2;   // C/D: row=(l>>4)*4+r, col=l&15
        outp[rowg * ldo + colg] = f2bf(fmaxf(acc[mi][ni][r2] + bs, 0.f));
      }
    }
  }
}

// ---------------- generic 128x128 bf16 GEMM (R4-verified) ----------------
__device__ __forceinline__ int lds_off(int row, int g) {
  int slot = (g + (row >> 1)) & 3;
  return row * 32 + slot * 8;                 // ushort units, ld=32
}

template<bool RELU, bool OUTBF16>
__global__ __launch_bounds__(256)
void k_gemm_bt(const unsigned short* __restrict__ A, const unsigned short* __restrict__ B,
               const float* __restrict__ bias, int bias_n, int nNt, int N_store, int K,
               void* __restrict__ outp, int ldo, int remap) {
  __shared__ __align__(16) unsigned short As[128 * 32];
  __shared__ __align__(16) unsigned short Bs[128 * 32];
  int d = blockIdx.x, nwg = gridDim.x;
  int L = d;
  if (remap) { int q = nwg >> 3; L = (d & 7) * q + (d >> 3); }  // only used when nwg % 8 == 0
  int mt = L / nNt, nt = L - mt * nNt;
  size_t m0 = (size_t)mt * 128, n0 = (size_t)nt * 128;
  int tid = threadIdx.x, lane = tid & 63;
  int w = tid >> 6, wr = w >> 1, wc = w & 1;
  int sr = tid >> 2;
  int gch = ((tid & 3) - (tid >> 3)) & 3;
  const unsigned short* pA0 = A + (m0 + sr) * K + gch * 8;
  const unsigned short* pA1 = pA0 + (size_t)64 * K;
  const unsigned short* pB0 = B + (n0 + sr) * K + gch * 8;
  const unsigned short* pB1 = pB0 + (size_t)64 * K;
  unsigned short* lA0 = &As[(tid & ~63) * 8];
  unsigned short* lA1 = &As[64 * 32 + (tid & ~63) * 8];
  unsigned short* lB0 = &Bs[(tid & ~63) * 8];
  unsigned short* lB1 = &Bs[64 * 32 + (tid & ~63) * 8];

  int kg = lane >> 4, l15 = lane & 15;
  int aoff = lds_off(wr * 64 + l15, kg);
  int boff = lds_off(wc * 64 + l15, kg);

  f32x4 acc[4][4];
  #pragma unroll
  for (int i = 0; i < 4; ++i)
    #pragma unroll
    for (int j = 0; j < 4; ++j) acc[i][j] = (f32x4)(0.f);

  for (int k0 = 0; k0 < K; k0 += 32) {
    __syncthreads();
    gl_lds16(pA0 + k0, lA0);
    gl_lds16(pA1 + k0, lA1);
    gl_lds16(pB0 + k0, lB0);
    gl_lds16(pB1 + k0, lB1);
    __syncthreads();
    short8 af[4], bfr[4];
    #pragma unroll
    for (int mi = 0; mi < 4; ++mi) af[mi] = *(const short8*)&As[aoff + mi * 512];
    #pragma unroll
    for (int ni = 0; ni < 4; ++ni) bfr[ni] = *(const short8*)&Bs[boff + ni * 512];
    #pragma unroll
    for (int mi = 0; mi < 4; ++mi)
      #pragma unroll
      for (int ni = 0; ni < 4; ++ni)
        acc[mi][ni] = __builtin_amdgcn_mfma_f32_16x16x32_bf16(af[mi], bfr[ni], acc[mi][ni], 0, 0, 0);
  }

  #pragma unroll
  for (int ni = 0; ni < 4; ++ni) {
    int colg = (int)n0 + wc * 64 + ni * 16 + l15;
    if (colg < N_store) {
      float bs = bias ? (colg < bias_n ? bias[colg] : 0.f) : 0.f;
      #pragma unroll
      for (int mi = 0; mi < 4; ++mi) {
        #pragma unroll
        for (int r2 = 0; r2 < 4; ++r2) {
          size_t rowg = m0 + wr * 64 + mi * 16 + kg * 4 + r2;
          float v = acc[mi][ni][r2] + bs;
          if (RELU) v = fmaxf(v, 0.f);
          if (OUTBF16) ((unsigned short*)outp)[rowg * ldo + colg] = f2bf(v);
          else         ((float*)outp)[rowg * ldo + colg] = v;
        }
      }
    }
  }
}

// ------- H1c[r_local] = relu(V1[src] + A1p[arow]) -> bf16  (b1a pre-folded into A1p) -------
__global__ void k_build_h1(const float* __restrict__ V1, const float* __restrict__ A1p,
                           const int* __restrict__ idx, unsigned short* __restrict__ H1c,
                           int rbase) {
  int row = rbase + blockIdx.x;                // global row 0..133119
  int src, arow;
  if (row < 2048) { src = row; arow = row; }   // rows 0..2047 = query
  else {
    int g = row - 2048; arow = g >> 6;
    int s = idx[g];
    src = s < 0 ? 0 : (s > 2047 ? 2047 : s);
  }
  int j = threadIdx.x * 4;
  float4 v = *(const float4*)(V1 + (size_t)src * 1024 + j);
  float4 a = *(const float4*)(A1p + (size_t)arow * 1024 + j);
  ushort4v o;
  o.x = f2bf(fmaxf(v.x + a.x, 0.f));
  o.y = f2bf(fmaxf(v.y + a.y, 0.f));
  o.z = f2bf(fmaxf(v.z + a.z, 0.f));
  o.w = f2bf(fmaxf(v.w + a.w, 0.f));
  *(ushort4v*)(H1c + (size_t)blockIdx.x * 1024 + j) = o;
}

// ---------------- logits[b,k] = dot(P[b], P[2048 + b*64 + k]) / T  (P is bf16) ----------------
__global__ void k_dot(const unsigned short* __restrict__ P, float* __restrict__ out) {
  __shared__ float q[128];
  int b = blockIdx.x, t = threadIdx.x;
  if (t < 128) q[t] = bf2f(P[(size_t)b * 128 + t]);
  __syncthreads();
  int k = t >> 2, part = t & 3;
  const unsigned short* row = P + (size_t)(2048 + b * 64 + k) * 128 + part * 32;
  const float* qp = q + part * 32;
  float s = 0.f;
  #pragma unroll
  for (int j = 0; j < 32; j += 8) {
    short8 pv = *(const short8*)(row + j);
    #pragma unroll
    for (int e = 0; e < 8; ++e)
      s += bf2f((unsigned short)pv[e]) * qp[j + e];
  }
  s += __shfl_xor(s, 1);
  s += __shfl_xor(s, 2);
  if (part == 0) out[(size_t)b * 64 + k] = s * (float)(1.0 / 0.12);
}

extern "C" void kernel_launch(void* const* d_in, const int* in_sizes, int n_in,
                              void* d_out, int out_size, void* d_ws, size_t ws_size,
                              hipStream_t stream) {
  const float* v2s = (const float*)d_in[0];
  const float* tar = (const float*)d_in[1];
  const int*   sidx = (const int*)d_in[2];
  const float* W2a = (const float*)d_in[3];
  const float* b2a = (const float*)d_in[4];
  const float* W2b = (const float*)d_in[5];
  const float* b2b = (const float*)d_in[6];
  const float* W2c = (const float*)d_in[7];
  const float* b2c = (const float*)d_in[8];
  const float* W1a = (const float*)d_in[9];
  const float* b1a = (const float*)d_in[10];
  const float* W1b = (const float*)d_in[11];
  const float* b1b = (const float*)d_in[12];
  const float* W1c = (const float*)d_in[13];
  const float* b1c = (const float*)d_in[14];
  float* out = (float*)d_out;

  // ---- workspace layout: persistent region + overlay (early att-MLP temps / late chunk bufs)
  char* ws = (char*)d_ws;
  size_t off = 0;
  auto alloc = [&](size_t bytes) -> char* {
    char* p = ws + off; off += (bytes + 255) & ~(size_t)255; return p;
  };
  // persistent
  unsigned short* W1bT = (unsigned short*)alloc(2048ull * 1024 * 2);  // [2048][1024]
  unsigned short* W1cT = (unsigned short*)alloc(128ull * 2048 * 2);   // [128][2048]
  float*          V1   = (float*)alloc(2048ull * 1024 * 4);           // v2s @ W1a
  float*          A1p  = (float*)alloc(2048ull * 1024 * 4);           // att @ W1a + b1a
  unsigned short* Pb   = (unsigned short*)alloc(133120ull * 128 * 2); // bf16 projections
  // overlay
  size_t O = off;
  // early (dead before chunk loop starts)
  off = O;
  unsigned short* W1aT = (unsigned short*)alloc(1024ull * 320 * 2);   // [1024][320]  (K-pad)
  unsigned short* v2sb = (unsigned short*)alloc(2048ull * 320 * 2);
  unsigned short* attb = (unsigned short*)alloc(2048ull * 320 * 2);
  unsigned short* W2bT = (unsigned short*)alloc(2048ull * 1024 * 2);
  unsigned short* W2cT = (unsigned short*)alloc(384ull * 2048 * 2);   // [384][2048]  (N-pad)
  unsigned short* h_a  = (unsigned short*)alloc(2048ull * 1024 * 2);
  unsigned short* h2a  = (unsigned short*)alloc(2048ull * 2048 * 2);
  size_t early_end = off;

  // adaptive chunk count: prefer chunks with R % 256 == 0 (256-tile GEMM); NCH=16 fallback.
  const int cands[4] = {1, 2, 4, 8};
  int NCH = -1, R = 0;
  for (int ci = 0; ci < 4; ++ci) {
    int c = cands[ci];
    size_t Rr = 133120ull / c;
    size_t late = O + (((Rr * 1024 * 2) + 255) & ~(size_t)255)
                    + (((Rr * 2048 * 2) + 255) & ~(size_t)255);
    size_t need = late > early_end ? late : early_end;
    if (need <= ws_size) { NCH = c; R = (int)Rr; break; }
  }
  int use256 = (NCH > 0);
  if (NCH < 0) {
    size_t Rr = 133120ull / 16;
    size_t late = O + (((Rr * 1024 * 2) + 255) & ~(size_t)255)
                    + (((Rr * 2048 * 2) + 255) & ~(size_t)255);
    size_t need = late > early_end ? late : early_end;
    if (need <= ws_size) { NCH = 16; R = (int)Rr; }
  }
  fprintf(stderr, "[kernel_launch] ws_size=%zu NCH=%d use256=%d\n", ws_size, NCH, use256);
  if (NCH < 0) {   // diagnostic fallback: zero output, no OOB write
    hipMemsetAsync(d_out, 0, (size_t)out_size * 4, stream);
    return;
  }
  off = O;
  unsigned short* H1c = (unsigned short*)alloc((size_t)R * 1024 * 2);
  unsigned short* H2c = (unsigned short*)alloc((size_t)R * 2048 * 2);

  dim3 blk(256);
  // weight prep
  k_transpose_cast<<<dim3(4, 2048), blk, 0, stream>>>(W2b, W2bT, 2048, 1024, 1024);
  k_transpose_cast<<<dim3(8, 384),  blk, 0, stream>>>(W2c, W2cT, 312, 2048, 2048);
  k_transpose_cast<<<dim3(2, 1024), blk, 0, stream>>>(W1a, W1aT, 1024, 312, 320);
  k_transpose_cast<<<dim3(4, 2048), blk, 0, stream>>>(W1b, W1bT, 2048, 1024, 1024);
  k_transpose_cast<<<dim3(8, 128),  blk, 0, stream>>>(W1c, W1cT, 128, 2048, 2048);
  k_att_l1<<<8192, blk, 0, stream>>>(tar, W2a, b2a, h_a);
  k_v2s_cast<<<2560, blk, 0, stream>>>(v2s, v2sb);
  // att MLP: h2a = relu(h_a @ W2b + b2b); attb = relu(h2a @ W2c + b2c) (cols 312..319 = 0)
  k_gemm_bt<true,  true ><<<256, blk, 0, stream>>>(h_a,  W2bT, b2b, 2048, 16, 2048, 1024, h2a,  2048, 1);
  k_gemm_bt<true,  true ><<<48,  blk, 0, stream>>>(h2a,  W2cT, b2c, 312,  3,  320,  2048, attb, 320,  1);
  // layer-1 factored: V1 = v2s@W1a (no bias); A1p = att@W1a + b1a  (f32 out, no act)
  k_gemm_bt<false, false><<<128, blk, 0, stream>>>(v2sb, W1aT, nullptr, 0,  8, 1024, 320, V1,  1024, 1);
  k_gemm_bt<false, false><<<128, blk, 0, stream>>>(attb, W1aT, b1a, 1024,  8, 1024, 320, A1p, 1024, 1);
  // chunked: build H1 -> layer2 (256-tile 8-phase) -> layer3
  for (int c = 0; c < NCH; ++c) {
    int rbase = c * R;
    k_build_h1<<<R, blk, 0, stream>>>(V1, A1p, sidx, H1c, rbase);
    if (use256)
      k_gemm256p8<<<(R / 256) * 8, dim3(512), 0, stream>>>(H1c, W1bT, b1b, 8, 1024, H2c, 2048);
    else
      k_gemm_bt<true, true><<<(R / 128) * 16, blk, 0, stream>>>(H1c, W1bT, b1b, 2048, 16, 2048, 1024, H2c, 2048, 1);
    k_gemm_bt<true, true><<<(R / 128), blk, 0, stream>>>(H2c, W1cT, b1c, 128, 1, 128, 2048,
                                                          Pb + (size_t)rbase * 128, 128, 0);
  }
  // logits
  k_dot<<<2048, blk, 0, stream>>>(Pb, out);
}

// Round 7
// 1082.157 us; speedup vs baseline: 1.5219x; 1.0562x over previous
//
#include <hip/hip_runtime.h>
#include <stdio.h>
#include <stdint.h>

typedef __attribute__((ext_vector_type(8))) short short8;     // 8 x bf16 bits (4 VGPRs)
typedef __attribute__((ext_vector_type(4))) float f32x4;      // MFMA accum
typedef __attribute__((ext_vector_type(4))) unsigned short ushort4v;

__device__ __forceinline__ unsigned short f2bf(float f) {
  unsigned int u = __builtin_bit_cast(unsigned int, f);
  u = u + 0x7FFFu + ((u >> 16) & 1u);   // RNE
  return (unsigned short)(u >> 16);
}
__device__ __forceinline__ float bf2f(unsigned short h) {
  unsigned int u = ((unsigned int)h) << 16;
  return __builtin_bit_cast(float, u);
}

// async global->LDS, 16B per lane; LDS dest = wave-uniform base + lane*16
__device__ __forceinline__ void gl_lds16(const unsigned short* g, unsigned short* l) {
  __builtin_amdgcn_global_load_lds(
      (const __attribute__((address_space(1))) unsigned int*)(const void*)g,
      (__attribute__((address_space(3))) unsigned int*)(void*)l, 16, 0, 0);
}

#define RAW_BAR()  asm volatile("s_barrier" ::: "memory")
#define LGKM0()    asm volatile("s_waitcnt lgkmcnt(0)" ::: "memory")
#define VMCNT(n_)  asm volatile("s_waitcnt vmcnt(" #n_ ")" ::: "memory")

// -------- tiled transpose+cast (+zero pad): out[n][k] = f2bf(in[k][n]); coalesced both sides --------
// grid (ldo/64, Nout/64), 256 thr. LDS 64x65 f32 (2-way bank aliasing = free).
__global__ void k_transpose_cast_t(const float* __restrict__ in, unsigned short* __restrict__ out,
                                   int Nin, int Kin, int ldo) {
  __shared__ float lds[64][65];
  int k0 = blockIdx.x * 64, n0 = blockIdx.y * 64;
  int t = threadIdx.x, tc = t & 15, tr = t >> 4;
  #pragma unroll
  for (int rr = 0; rr < 4; ++rr) {
    int kl = tr + rr * 16, k = k0 + kl;
    #pragma unroll
    for (int j = 0; j < 4; ++j) {
      int nl = tc * 4 + j, n = n0 + nl;
      lds[kl][nl] = (k < Kin && n < Nin) ? in[(size_t)k * Nin + n] : 0.f;
    }
  }
  __syncthreads();
  #pragma unroll
  for (int rr = 0; rr < 4; ++rr) {
    int nl = tr + rr * 16, n = n0 + nl;
    int kb = k0 + tc * 4;
    if (kb + 3 < ldo) {
      ushort4v o;
      o.x = f2bf(lds[tc * 4 + 0][nl]);
      o.y = f2bf(lds[tc * 4 + 1][nl]);
      o.z = f2bf(lds[tc * 4 + 2][nl]);
      o.w = f2bf(lds[tc * 4 + 3][nl]);
      *(ushort4v*)&out[(size_t)n * ldo + kb] = o;
    } else {
      for (int j = 0; j < 4; ++j)
        if (kb + j < ldo) out[(size_t)n * ldo + kb + j] = f2bf(lds[tc * 4 + j][nl]);
    }
  }
}

// ---------------- att layer 1: h = relu(t[b]*W2a[j] + b2a[j]) -> bf16 [2048x1024] ----------------
__global__ void k_att_l1(const float* __restrict__ tar, const float* __restrict__ W2a,
                         const float* __restrict__ b2a, unsigned short* __restrict__ out) {
  int id = blockIdx.x * 256 + threadIdx.x;   // 2048*1024
  int b = id >> 10, j = id & 1023;
  out[id] = f2bf(fmaxf(tar[b] * W2a[j] + b2a[j], 0.f));
}

// ---------------- v2s cast to bf16, K padded 312->320 ----------------
__global__ void k_v2s_cast(const float* __restrict__ v2s, unsigned short* __restrict__ out) {
  int id = blockIdx.x * 256 + threadIdx.x;   // 2048*320
  int r = id / 320, c = id - r * 320;
  out[id] = (c < 312) ? f2bf(v2s[(size_t)r * 312 + c]) : (unsigned short)0;
}

// ======== 256x256 8-phase GEMM (T3+T4+T5): C = relu(A[M x K] @ BT[N x K]^T + bias) ========
// (unchanged from R6 — verified correct; see R6 header comment for schedule/liveness proof)
__global__ __launch_bounds__(512, 2)
void k_gemm256p8(const unsigned short* __restrict__ A, const unsigned short* __restrict__ B,
                 const float* __restrict__ bias, int nNt, int K,
                 unsigned short* __restrict__ outp, int ldo) {
  __shared__ __align__(16) unsigned short sm[65536];   // 128 KiB
  int d0 = blockIdx.x, nwg = gridDim.x;
  int q = nwg >> 3;                            // nwg % 8 == 0 guaranteed by launcher
  int L = (d0 & 7) * q + (d0 >> 3);            // XCD-contiguous chunks
  int mt = L / nNt, nt = L - mt * nNt;
  size_t m0 = (size_t)mt * 256, n0 = (size_t)nt * 256;
  int tid = threadIdx.x, lane = tid & 63;
  int w = tid >> 6, wr = w >> 2, wc = w & 3;

  int srow = tid >> 3;
  int gch = ((tid & 7) - srow) & 7;            // inverse swizzle on global src (rule #21)
  const unsigned short* Asrc = A + (m0 + srow) * K + gch * 8;
  const unsigned short* Bsrc = B + (n0 + srow) * K + gch * 8;
  int sdst = w * 512;                          // wave-uniform; HW adds lane*16B

#define STAGE_A(u_, h_) do { int db_ = ((u_) & 1) * 32768, ko_ = (u_) * 64;          \
    gl_lds16(Asrc + ((h_) * 128 + 0 ) * K + ko_, sm + db_ + (h_) * 8192 + 0    + sdst); \
    gl_lds16(Asrc + ((h_) * 128 + 64) * K + ko_, sm + db_ + (h_) * 8192 + 4096 + sdst); \
  } while (0)
#define STAGE_B(u_, h_) do { int db_ = ((u_) & 1) * 32768 + 16384, ko_ = (u_) * 64;  \
    gl_lds16(Bsrc + ((h_) * 128 + 0 ) * K + ko_, sm + db_ + (h_) * 8192 + 0    + sdst); \
    gl_lds16(Bsrc + ((h_) * 128 + 64) * K + ko_, sm + db_ + (h_) * 8192 + 4096 + sdst); \
  } while (0)

  int kg = lane >> 4, l15 = lane & 15;
  int CA = wr * 128 + l15;
  int CB = wc * 64 + l15;
  int aoffs[2] = { CA * 64 + ((kg + CA) & 7) * 8, CA * 64 + ((kg + CA + 4) & 7) * 8 };
  int boffs[2] = { CB * 64 + ((kg + CB) & 7) * 8, CB * 64 + ((kg + CB + 4) & 7) * 8 };

  f32x4 acc[8][4];
  #pragma unroll
  for (int i = 0; i < 8; ++i)
    #pragma unroll
    for (int j = 0; j < 4; ++j) acc[i][j] = (f32x4)(0.f);

  const int NT = K >> 6;

  STAGE_A(0, 0); STAGE_A(0, 1); STAGE_B(0, 0); STAGE_B(0, 1);
  STAGE_B(1, 0); STAGE_B(1, 1);
  VMCNT(4);
  RAW_BAR();

  short8 af[4][2], bfv[4][2];
  for (int u = 0; u < NT; ++u) {
    const unsigned short* Ab = sm + (u & 1) * 32768;
    const unsigned short* Bb = Ab + 16384;
    // ---- P0
    #pragma unroll
    for (int mi = 0; mi < 4; ++mi)
      #pragma unroll
      for (int ks = 0; ks < 2; ++ks) af[mi][ks] = *(const short8*)&Ab[aoffs[ks] + mi * 1024];
    #pragma unroll
    for (int ni = 0; ni < 2; ++ni)
      #pragma unroll
      for (int ks = 0; ks < 2; ++ks) bfv[ni][ks] = *(const short8*)&Bb[boffs[ks] + ni * 1024];
    if (u + 1 < NT) STAGE_A(u + 1, 0);
    RAW_BAR(); LGKM0();
    __builtin_amdgcn_s_setprio(1);
    #pragma unroll
    for (int mi = 0; mi < 4; ++mi)
      #pragma unroll
      for (int ni = 0; ni < 2; ++ni)
        #pragma unroll
        for (int ks = 0; ks < 2; ++ks)
          acc[mi][ni] = __builtin_amdgcn_mfma_f32_16x16x32_bf16(af[mi][ks], bfv[ni][ks], acc[mi][ni], 0, 0, 0);
    __builtin_amdgcn_s_setprio(0);
    RAW_BAR();
    // ---- P1
    #pragma unroll
    for (int ni = 2; ni < 4; ++ni)
      #pragma unroll
      for (int ks = 0; ks < 2; ++ks) bfv[ni][ks] = *(const short8*)&Bb[boffs[ks] + ni * 1024];
    if (u + 1 < NT) STAGE_A(u + 1, 1);
    RAW_BAR(); LGKM0();
    __builtin_amdgcn_s_setprio(1);
    #pragma unroll
    for (int mi = 0; mi < 4; ++mi)
      #pragma unroll
      for (int ni = 2; ni < 4; ++ni)
        #pragma unroll
        for (int ks = 0; ks < 2; ++ks)
          acc[mi][ni] = __builtin_amdgcn_mfma_f32_16x16x32_bf16(af[mi][ks], bfv[ni][ks], acc[mi][ni], 0, 0, 0);
    __builtin_amdgcn_s_setprio(0);
    RAW_BAR();
    // ---- P2
    #pragma unroll
    for (int mi = 0; mi < 4; ++mi)
      #pragma unroll
      for (int ks = 0; ks < 2; ++ks) af[mi][ks] = *(const short8*)&Ab[aoffs[ks] + (mi + 4) * 1024];
    if (u + 2 < NT) STAGE_B(u + 2, 0);
    RAW_BAR(); LGKM0();
    __builtin_amdgcn_s_setprio(1);
    #pragma unroll
    for (int mi = 0; mi < 4; ++mi)
      #pragma unroll
      for (int ni = 0; ni < 2; ++ni)
        #pragma unroll
        for (int ks = 0; ks < 2; ++ks)
          acc[mi + 4][ni] = __builtin_amdgcn_mfma_f32_16x16x32_bf16(af[mi][ks], bfv[ni][ks], acc[mi + 4][ni], 0, 0, 0);
    __builtin_amdgcn_s_setprio(0);
    RAW_BAR();
    // ---- P3
    if (u + 2 < NT) STAGE_B(u + 2, 1);
    __builtin_amdgcn_s_setprio(1);
    #pragma unroll
    for (int mi = 0; mi < 4; ++mi)
      #pragma unroll
      for (int ni = 2; ni < 4; ++ni)
        #pragma unroll
        for (int ks = 0; ks < 2; ++ks)
          acc[mi + 4][ni] = __builtin_amdgcn_mfma_f32_16x16x32_bf16(af[mi][ks], bfv[ni][ks], acc[mi + 4][ni], 0, 0, 0);
    __builtin_amdgcn_s_setprio(0);
    if (u + 1 < NT) {
      if (u + 2 < NT) { VMCNT(4); }
      else            { VMCNT(0); }
      RAW_BAR();
    }
  }
#undef STAGE_A
#undef STAGE_B

  #pragma unroll
  for (int ni = 0; ni < 4; ++ni) {
    int colg = (int)n0 + wc * 64 + ni * 16 + l15;
    float bs = bias[colg];
    #pragma unroll
    for (int mi = 0; mi < 8; ++mi) {
      #pragma unroll
      for (int r2 = 0; r2 < 4; ++r2) {
        size_t rowg = m0 + wr * 128 + mi * 16 + kg * 4 + r2;
        outp[rowg * ldo + colg] = f2bf(fmaxf(acc[mi][ni][r2] + bs, 0.f));
      }
    }
  }
}

// ---------------- generic 128x128 bf16 GEMM (R4-verified) ----------------
__device__ __forceinline__ int lds_off(int row, int g) {
  int slot = (g + (row >> 1)) & 3;
  return row * 32 + slot * 8;                 // ushort units, ld=32
}

template<bool RELU, bool OUTBF16>
__global__ __launch_bounds__(256)
void k_gemm_bt(const unsigned short* __restrict__ A, const unsigned short* __restrict__ B,
               const float* __restrict__ bias, int bias_n, int nNt, int N_store, int K,
               void* __restrict__ outp, int ldo, int remap) {
  __shared__ __align__(16) unsigned short As[128 * 32];
  __shared__ __align__(16) unsigned short Bs[128 * 32];
  int d = blockIdx.x, nwg = gridDim.x;
  int L = d;
  if (remap) { int q = nwg >> 3; L = (d & 7) * q + (d >> 3); }  // only used when nwg % 8 == 0
  int mt = L / nNt, nt = L - mt * nNt;
  size_t m0 = (size_t)mt * 128, n0 = (size_t)nt * 128;
  int tid = threadIdx.x, lane = tid & 63;
  int w = tid >> 6, wr = w >> 1, wc = w & 1;
  int sr = tid >> 2;
  int gch = ((tid & 3) - (tid >> 3)) & 3;
  const unsigned short* pA0 = A + (m0 + sr) * K + gch * 8;
  const unsigned short* pA1 = pA0 + (size_t)64 * K;
  const unsigned short* pB0 = B + (n0 + sr) * K + gch * 8;
  const unsigned short* pB1 = pB0 + (size_t)64 * K;
  unsigned short* lA0 = &As[(tid & ~63) * 8];
  unsigned short* lA1 = &As[64 * 32 + (tid & ~63) * 8];
  unsigned short* lB0 = &Bs[(tid & ~63) * 8];
  unsigned short* lB1 = &Bs[64 * 32 + (tid & ~63) * 8];

  int kg = lane >> 4, l15 = lane & 15;
  int aoff = lds_off(wr * 64 + l15, kg);
  int boff = lds_off(wc * 64 + l15, kg);

  f32x4 acc[4][4];
  #pragma unroll
  for (int i = 0; i < 4; ++i)
    #pragma unroll
    for (int j = 0; j < 4; ++j) acc[i][j] = (f32x4)(0.f);

  for (int k0 = 0; k0 < K; k0 += 32) {
    __syncthreads();
    gl_lds16(pA0 + k0, lA0);
    gl_lds16(pA1 + k0, lA1);
    gl_lds16(pB0 + k0, lB0);
    gl_lds16(pB1 + k0, lB1);
    __syncthreads();
    short8 af[4], bfr[4];
    #pragma unroll
    for (int mi = 0; mi < 4; ++mi) af[mi] = *(const short8*)&As[aoff + mi * 512];
    #pragma unroll
    for (int ni = 0; ni < 4; ++ni) bfr[ni] = *(const short8*)&Bs[boff + ni * 512];
    #pragma unroll
    for (int mi = 0; mi < 4; ++mi)
      #pragma unroll
      for (int ni = 0; ni < 4; ++ni)
        acc[mi][ni] = __builtin_amdgcn_mfma_f32_16x16x32_bf16(af[mi], bfr[ni], acc[mi][ni], 0, 0, 0);
  }

  #pragma unroll
  for (int ni = 0; ni < 4; ++ni) {
    int colg = (int)n0 + wc * 64 + ni * 16 + l15;
    if (colg < N_store) {
      float bs = bias ? (colg < bias_n ? bias[colg] : 0.f) : 0.f;
      #pragma unroll
      for (int mi = 0; mi < 4; ++mi) {
        #pragma unroll
        for (int r2 = 0; r2 < 4; ++r2) {
          size_t rowg = m0 + wr * 64 + mi * 16 + kg * 4 + r2;
          float v = acc[mi][ni][r2] + bs;
          if (RELU) v = fmaxf(v, 0.f);
          if (OUTBF16) ((unsigned short*)outp)[rowg * ldo + colg] = f2bf(v);
          else         ((float*)outp)[rowg * ldo + colg] = v;
        }
      }
    }
  }
}

// ------- H1c[r_local] = relu(V1[src] + A1p[arow]) -> bf16  (b1a pre-folded into A1p) -------
__global__ void k_build_h1(const float* __restrict__ V1, const float* __restrict__ A1p,
                           const int* __restrict__ idx, unsigned short* __restrict__ H1c,
                           int rbase) {
  int row = rbase + blockIdx.x;                // global row 0..133119
  int src, arow;
  if (row < 2048) { src = row; arow = row; }   // rows 0..2047 = query
  else {
    int g = row - 2048; arow = g >> 6;
    int s = idx[g];
    src = s < 0 ? 0 : (s > 2047 ? 2047 : s);
  }
  int j = threadIdx.x * 4;
  float4 v = *(const float4*)(V1 + (size_t)src * 1024 + j);
  float4 a = *(const float4*)(A1p + (size_t)arow * 1024 + j);
  ushort4v o;
  o.x = f2bf(fmaxf(v.x + a.x, 0.f));
  o.y = f2bf(fmaxf(v.y + a.y, 0.f));
  o.z = f2bf(fmaxf(v.z + a.z, 0.f));
  o.w = f2bf(fmaxf(v.w + a.w, 0.f));
  *(ushort4v*)(H1c + (size_t)blockIdx.x * 1024 + j) = o;
}

// ---------------- logits[b,k] = dot(P[b], P[2048 + b*64 + k]) / T  (P is bf16) ----------------
__global__ void k_dot(const unsigned short* __restrict__ P, float* __restrict__ out) {
  __shared__ float q[128];
  int b = blockIdx.x, t = threadIdx.x;
  if (t < 128) q[t] = bf2f(P[(size_t)b * 128 + t]);
  __syncthreads();
  int k = t >> 2, part = t & 3;
  const unsigned short* row = P + (size_t)(2048 + b * 64 + k) * 128 + part * 32;
  const float* qp = q + part * 32;
  float s = 0.f;
  #pragma unroll
  for (int j = 0; j < 32; j += 8) {
    short8 pv = *(const short8*)(row + j);
    #pragma unroll
    for (int e = 0; e < 8; ++e)
      s += bf2f((unsigned short)pv[e]) * qp[j + e];
  }
  s += __shfl_xor(s, 1);
  s += __shfl_xor(s, 2);
  if (part == 0) out[(size_t)b * 64 + k] = s * (float)(1.0 / 0.12);
}

extern "C" void kernel_launch(void* const* d_in, const int* in_sizes, int n_in,
                              void* d_out, int out_size, void* d_ws, size_t ws_size,
                              hipStream_t stream) {
  const float* v2s = (const float*)d_in[0];
  const float* tar = (const float*)d_in[1];
  const int*   sidx = (const int*)d_in[2];
  const float* W2a = (const float*)d_in[3];
  const float* b2a = (const float*)d_in[4];
  const float* W2b = (const float*)d_in[5];
  const float* b2b = (const float*)d_in[6];
  const float* W2c = (const float*)d_in[7];
  const float* b2c = (const float*)d_in[8];
  const float* W1a = (const float*)d_in[9];
  const float* b1a = (const float*)d_in[10];
  const float* W1b = (const float*)d_in[11];
  const float* b1b = (const float*)d_in[12];
  const float* W1c = (const float*)d_in[13];
  const float* b1c = (const float*)d_in[14];
  float* out = (float*)d_out;

  char* ws = (char*)d_ws;
  size_t off = 0;
  auto alloc = [&](size_t bytes) -> char* {
    char* p = ws + off; off += (bytes + 255) & ~(size_t)255; return p;
  };
  // persistent
  unsigned short* W1bT = (unsigned short*)alloc(2048ull * 1024 * 2);  // [2048][1024]
  unsigned short* W1cT = (unsigned short*)alloc(128ull * 2048 * 2);   // [128][2048]
  float*          V1   = (float*)alloc(2048ull * 1024 * 4);           // v2s @ W1a
  float*          A1p  = (float*)alloc(2048ull * 1024 * 4);           // att @ W1a + b1a
  unsigned short* Pb   = (unsigned short*)alloc(133120ull * 128 * 2); // bf16 projections
  // overlay
  size_t O = off;
  off = O;
  unsigned short* W1aT = (unsigned short*)alloc(1024ull * 320 * 2);   // [1024][320]  (K-pad)
  unsigned short* v2sb = (unsigned short*)alloc(2048ull * 320 * 2);
  unsigned short* attb = (unsigned short*)alloc(2048ull * 320 * 2);
  unsigned short* W2bT = (unsigned short*)alloc(2048ull * 1024 * 2);
  unsigned short* W2cT = (unsigned short*)alloc(384ull * 2048 * 2);   // [384][2048]  (N-pad)
  unsigned short* h_a  = (unsigned short*)alloc(2048ull * 1024 * 2);
  unsigned short* h2a  = (unsigned short*)alloc(2048ull * 2048 * 2);
  size_t early_end = off;

  // ---- chunk plans: m-tiles (x256 rows) per chunk, sum = 520. Round-exact grids preferred
  // (1056/1024 blocks -> ~4.1/4.0 rounds at 1 block/CU) to kill dispatch-tail waste.
  static const int plans[4][8] = {{260,260,0,0,0,0,0,0},
                                  {132,132,128,128,0,0,0,0},
                                  {130,130,130,130,0,0,0,0},
                                  {65,65,65,65,65,65,65,65}};
  int sel = -1, maxmt = 0;
  for (int p = 0; p < 4 && sel < 0; ++p) {
    int mx = 0;
    for (int i = 0; i < 8; ++i) if (plans[p][i] > mx) mx = plans[p][i];
    size_t rows = (size_t)mx * 256;
    size_t late = O + ((rows * 1024 * 2 + 255) & ~(size_t)255)
                    + ((rows * 2048 * 2 + 255) & ~(size_t)255);
    size_t need = late > early_end ? late : early_end;
    if (need <= ws_size) { sel = p; maxmt = mx; }
  }
  int use256 = (sel >= 0);
  int fallR = 0;
  if (!use256) {   // NCH=16 fallback on 128-tile path
    size_t rows = 133120ull / 16;
    size_t late = O + ((rows * 1024 * 2 + 255) & ~(size_t)255)
                    + ((rows * 2048 * 2 + 255) & ~(size_t)255);
    size_t need = late > early_end ? late : early_end;
    if (need <= ws_size) fallR = (int)rows;
  }
  fprintf(stderr, "[kernel_launch] ws_size=%zu sel=%d use256=%d\n", ws_size, sel, use256);
  if (!use256 && !fallR) {
    hipMemsetAsync(d_out, 0, (size_t)out_size * 4, stream);
    return;
  }
  off = O;
  size_t bufrows = use256 ? (size_t)maxmt * 256 : (size_t)fallR;
  unsigned short* H1c = (unsigned short*)alloc(bufrows * 1024 * 2);
  unsigned short* H2c = (unsigned short*)alloc(bufrows * 2048 * 2);

  dim3 blk(256);
  // weight prep (tiled coalesced transpose)
  k_transpose_cast_t<<<dim3(16, 32), blk, 0, stream>>>(W2b, W2bT, 2048, 1024, 1024);
  k_transpose_cast_t<<<dim3(32, 6),  blk, 0, stream>>>(W2c, W2cT, 312, 2048, 2048);
  k_transpose_cast_t<<<dim3(5, 16),  blk, 0, stream>>>(W1a, W1aT, 1024, 312, 320);
  k_transpose_cast_t<<<dim3(16, 32), blk, 0, stream>>>(W1b, W1bT, 2048, 1024, 1024);
  k_transpose_cast_t<<<dim3(32, 2),  blk, 0, stream>>>(W1c, W1cT, 128, 2048, 2048);
  k_att_l1<<<8192, blk, 0, stream>>>(tar, W2a, b2a, h_a);
  k_v2s_cast<<<2560, blk, 0, stream>>>(v2s, v2sb);
  // att MLP
  k_gemm_bt<true,  true ><<<256, blk, 0, stream>>>(h_a,  W2bT, b2b, 2048, 16, 2048, 1024, h2a,  2048, 1);
  k_gemm_bt<true,  true ><<<48,  blk, 0, stream>>>(h2a,  W2cT, b2c, 312,  3,  320,  2048, attb, 320,  1);
  // layer-1 factored
  k_gemm_bt<false, false><<<128, blk, 0, stream>>>(v2sb, W1aT, nullptr, 0,  8, 1024, 320, V1,  1024, 1);
  k_gemm_bt<false, false><<<128, blk, 0, stream>>>(attb, W1aT, b1a, 1024,  8, 1024, 320, A1p, 1024, 1);
  // chunked: build H1 -> layer2 -> layer3
  if (use256) {
    int rbase = 0;
    for (int i = 0; i < 8 && plans[sel][i]; ++i) {
      int mtc = plans[sel][i];
      int R = mtc * 256;
      k_build_h1<<<R, blk, 0, stream>>>(V1, A1p, sidx, H1c, rbase);
      k_gemm256p8<<<mtc * 8, dim3(512), 0, stream>>>(H1c, W1bT, b1b, 8, 1024, H2c, 2048);
      k_gemm_bt<true, true><<<(R / 128), blk, 0, stream>>>(H2c, W1cT, b1c, 128, 1, 128, 2048,
                                                            Pb + (size_t)rbase * 128, 128, 0);
      rbase += R;
    }
  } else {
    for (int c = 0; c < 16; ++c) {
      int rbase = c * fallR;
      k_build_h1<<<fallR, blk, 0, stream>>>(V1, A1p, sidx, H1c, rbase);
      k_gemm_bt<true, true><<<(fallR / 128) * 16, blk, 0, stream>>>(H1c, W1bT, b1b, 2048, 16, 2048, 1024, H2c, 2048, 1);
      k_gemm_bt<true, true><<<(fallR / 128), blk, 0, stream>>>(H2c, W1cT, b1c, 128, 1, 128, 2048,
                                                                Pb + (size_t)rbase * 128, 128, 0);
    }
  }
  // logits
  k_dot<<<2048, blk, 0, stream>>>(Pb, out);
}

// Round 8
// 1075.955 us; speedup vs baseline: 1.5307x; 1.0058x over previous
//
#include <hip/hip_runtime.h>
#include <stdio.h>
#include <stdint.h>

typedef __attribute__((ext_vector_type(8))) short short8;     // 8 x bf16 bits (4 VGPRs)
typedef __attribute__((ext_vector_type(4))) float f32x4;      // MFMA accum
typedef __attribute__((ext_vector_type(4))) unsigned short ushort4v;

__device__ __forceinline__ unsigned short f2bf(float f) {
  unsigned int u = __builtin_bit_cast(unsigned int, f);
  u = u + 0x7FFFu + ((u >> 16) & 1u);   // RNE
  return (unsigned short)(u >> 16);
}
__device__ __forceinline__ float bf2f(unsigned short h) {
  unsigned int u = ((unsigned int)h) << 16;
  return __builtin_bit_cast(float, u);
}

// async global->LDS, 16B per lane; LDS dest = wave-uniform base + lane*16
__device__ __forceinline__ void gl_lds16(const unsigned short* g, unsigned short* l) {
  __builtin_amdgcn_global_load_lds(
      (const __attribute__((address_space(1))) unsigned int*)(const void*)g,
      (__attribute__((address_space(3))) unsigned int*)(void*)l, 16, 0, 0);
}

// -------- tiled transpose+cast (+zero pad): out[n][k] = f2bf(in[k][n]); coalesced both sides --------
__global__ void k_transpose_cast_t(const float* __restrict__ in, unsigned short* __restrict__ out,
                                   int Nin, int Kin, int ldo) {
  __shared__ float lds[64][65];
  int k0 = blockIdx.x * 64, n0 = blockIdx.y * 64;
  int t = threadIdx.x, tc = t & 15, tr = t >> 4;
  #pragma unroll
  for (int rr = 0; rr < 4; ++rr) {
    int kl = tr + rr * 16, k = k0 + kl;
    #pragma unroll
    for (int j = 0; j < 4; ++j) {
      int nl = tc * 4 + j, n = n0 + nl;
      lds[kl][nl] = (k < Kin && n < Nin) ? in[(size_t)k * Nin + n] : 0.f;
    }
  }
  __syncthreads();
  #pragma unroll
  for (int rr = 0; rr < 4; ++rr) {
    int nl = tr + rr * 16, n = n0 + nl;
    int kb = k0 + tc * 4;
    if (kb + 3 < ldo) {
      ushort4v o;
      o.x = f2bf(lds[tc * 4 + 0][nl]);
      o.y = f2bf(lds[tc * 4 + 1][nl]);
      o.z = f2bf(lds[tc * 4 + 2][nl]);
      o.w = f2bf(lds[tc * 4 + 3][nl]);
      *(ushort4v*)&out[(size_t)n * ldo + kb] = o;
    } else {
      for (int j = 0; j < 4; ++j)
        if (kb + j < ldo) out[(size_t)n * ldo + kb + j] = f2bf(lds[tc * 4 + j][nl]);
    }
  }
}

// ---------------- att layer 1: h = relu(t[b]*W2a[j] + b2a[j]) -> bf16 [2048x1024] ----------------
__global__ void k_att_l1(const float* __restrict__ tar, const float* __restrict__ W2a,
                         const float* __restrict__ b2a, unsigned short* __restrict__ out) {
  int id = blockIdx.x * 256 + threadIdx.x;   // 2048*1024
  int b = id >> 10, j = id & 1023;
  out[id] = f2bf(fmaxf(tar[b] * W2a[j] + b2a[j], 0.f));
}

// ---------------- v2s cast to bf16, K padded 312->320 ----------------
__global__ void k_v2s_cast(const float* __restrict__ v2s, unsigned short* __restrict__ out) {
  int id = blockIdx.x * 256 + threadIdx.x;   // 2048*320
  int r = id / 320, c = id - r * 320;
  out[id] = (c < 312) ? f2bf(v2s[(size_t)r * 312 + c]) : (unsigned short)0;
}

// ====== 128x128 bf16 GEMM, DOUBLE-BUFFERED (issue-early / drain-late; T3 minimum 2-phase) ======
// BK=32, 256 thr (2x2 waves of 64x64), 32KB LDS -> ~3 blocks/CU (occupancy) AND a full
// K-tile of slack between STAGE issue and the next barrier's implicit vmcnt(0) drain.
// Frag math / swizzle byte-identical to the R4-verified kernel (0 bank conflicts measured).
__device__ __forceinline__ int lds_off(int row, int g) {
  int slot = (g + (row >> 1)) & 3;
  return row * 32 + slot * 8;                 // ushort units, ld=32
}

template<bool RELU, bool OUTBF16>
__global__ __launch_bounds__(256)
void k_gemm_bt(const unsigned short* __restrict__ A, const unsigned short* __restrict__ B,
               const float* __restrict__ bias, int bias_n, int nNt, int N_store, int K,
               void* __restrict__ outp, int ldo, int remap) {
  __shared__ __align__(16) unsigned short As[2][4096];   // [buf][128 rows x 32]
  __shared__ __align__(16) unsigned short Bs[2][4096];
  int d = blockIdx.x, nwg = gridDim.x;
  int L = d;
  if (remap) { int q = nwg >> 3; L = (d & 7) * q + (d >> 3); }  // only used when nwg % 8 == 0
  int mt = L / nNt, nt = L - mt * nNt;
  size_t m0 = (size_t)mt * 128, n0 = (size_t)nt * 128;
  int tid = threadIdx.x, lane = tid & 63;
  int w = tid >> 6, wr = w >> 1, wc = w & 1;
  int sr = tid >> 2;
  int gch = ((tid & 3) - (tid >> 3)) & 3;     // pre-swizzled global chunk (rule #21)
  const unsigned short* pA0 = A + (m0 + sr) * K + gch * 8;
  const unsigned short* pA1 = pA0 + (size_t)64 * K;
  const unsigned short* pB0 = B + (n0 + sr) * K + gch * 8;
  const unsigned short* pB1 = pB0 + (size_t)64 * K;
  int sd = (tid & ~63) * 8;                   // wave-uniform dest; HW adds lane*16B

  int kg = lane >> 4, l15 = lane & 15;
  int aoff = lds_off(wr * 64 + l15, kg);
  int boff = lds_off(wc * 64 + l15, kg);

  f32x4 acc[4][4];
  #pragma unroll
  for (int i = 0; i < 4; ++i)
    #pragma unroll
    for (int j = 0; j < 4; ++j) acc[i][j] = (f32x4)(0.f);

  const int NT = K >> 5;                      // K % 32 == 0
#define STAGE(t_, b_) do { int k0_ = (t_) * 32;                       \
    gl_lds16(pA0 + k0_, &As[b_][sd]);                                 \
    gl_lds16(pA1 + k0_, &As[b_][2048 + sd]);                          \
    gl_lds16(pB0 + k0_, &Bs[b_][sd]);                                 \
    gl_lds16(pB1 + k0_, &Bs[b_][2048 + sd]);                          \
  } while (0)

  STAGE(0, 0);                                // prologue
  for (int t = 0; t < NT; ++t) {
    int b = t & 1;
    __syncthreads();                          // implicit vmcnt(0): stage(t) landed (issued 1 tile ago)
    if (t + 1 < NT) STAGE(t + 1, b ^ 1);      // issue EARLY -> full tile of slack before next drain
    short8 af[4], bfr[4];
    #pragma unroll
    for (int mi = 0; mi < 4; ++mi) af[mi] = *(const short8*)&As[b][aoff + mi * 512];
    #pragma unroll
    for (int ni = 0; ni < 4; ++ni) bfr[ni] = *(const short8*)&Bs[b][boff + ni * 512];
    #pragma unroll
    for (int mi = 0; mi < 4; ++mi)
      #pragma unroll
      for (int ni = 0; ni < 4; ++ni)
        acc[mi][ni] = __builtin_amdgcn_mfma_f32_16x16x32_bf16(af[mi], bfr[ni], acc[mi][ni], 0, 0, 0);
  }
#undef STAGE

  #pragma unroll
  for (int ni = 0; ni < 4; ++ni) {
    int colg = (int)n0 + wc * 64 + ni * 16 + l15;
    if (colg < N_store) {
      float bs = bias ? (colg < bias_n ? bias[colg] : 0.f) : 0.f;
      #pragma unroll
      for (int mi = 0; mi < 4; ++mi) {
        #pragma unroll
        for (int r2 = 0; r2 < 4; ++r2) {
          size_t rowg = m0 + wr * 64 + mi * 16 + kg * 4 + r2;   // C/D: row=(l>>4)*4+r, col=l&15
          float v = acc[mi][ni][r2] + bs;
          if (RELU) v = fmaxf(v, 0.f);
          if (OUTBF16) ((unsigned short*)outp)[rowg * ldo + colg] = f2bf(v);
          else         ((float*)outp)[rowg * ldo + colg] = v;
        }
      }
    }
  }
}

// ------- H1c[r_local] = relu(V1[src] + A1p[arow]) -> bf16  (b1a pre-folded into A1p) -------
__global__ void k_build_h1(const float* __restrict__ V1, const float* __restrict__ A1p,
                           const int* __restrict__ idx, unsigned short* __restrict__ H1c,
                           int rbase) {
  int row = rbase + blockIdx.x;                // global row 0..133119
  int src, arow;
  if (row < 2048) { src = row; arow = row; }   // rows 0..2047 = query
  else {
    int g = row - 2048; arow = g >> 6;
    int s = idx[g];
    src = s < 0 ? 0 : (s > 2047 ? 2047 : s);
  }
  int j = threadIdx.x * 4;
  float4 v = *(const float4*)(V1 + (size_t)src * 1024 + j);
  float4 a = *(const float4*)(A1p + (size_t)arow * 1024 + j);
  ushort4v o;
  o.x = f2bf(fmaxf(v.x + a.x, 0.f));
  o.y = f2bf(fmaxf(v.y + a.y, 0.f));
  o.z = f2bf(fmaxf(v.z + a.z, 0.f));
  o.w = f2bf(fmaxf(v.w + a.w, 0.f));
  *(ushort4v*)(H1c + (size_t)blockIdx.x * 1024 + j) = o;
}

// ---------------- logits[b,k] = dot(P[b], P[2048 + b*64 + k]) / T  (P is bf16) ----------------
__global__ void k_dot(const unsigned short* __restrict__ P, float* __restrict__ out) {
  __shared__ float q[128];
  int b = blockIdx.x, t = threadIdx.x;
  if (t < 128) q[t] = bf2f(P[(size_t)b * 128 + t]);
  __syncthreads();
  int k = t >> 2, part = t & 3;
  const unsigned short* row = P + (size_t)(2048 + b * 64 + k) * 128 + part * 32;
  const float* qp = q + part * 32;
  float s = 0.f;
  #pragma unroll
  for (int j = 0; j < 32; j += 8) {
    short8 pv = *(const short8*)(row + j);
    #pragma unroll
    for (int e = 0; e < 8; ++e)
      s += bf2f((unsigned short)pv[e]) * qp[j + e];
  }
  s += __shfl_xor(s, 1);
  s += __shfl_xor(s, 2);
  if (part == 0) out[(size_t)b * 64 + k] = s * (float)(1.0 / 0.12);
}

extern "C" void kernel_launch(void* const* d_in, const int* in_sizes, int n_in,
                              void* d_out, int out_size, void* d_ws, size_t ws_size,
                              hipStream_t stream) {
  const float* v2s = (const float*)d_in[0];
  const float* tar = (const float*)d_in[1];
  const int*   sidx = (const int*)d_in[2];
  const float* W2a = (const float*)d_in[3];
  const float* b2a = (const float*)d_in[4];
  const float* W2b = (const float*)d_in[5];
  const float* b2b = (const float*)d_in[6];
  const float* W2c = (const float*)d_in[7];
  const float* b2c = (const float*)d_in[8];
  const float* W1a = (const float*)d_in[9];
  const float* b1a = (const float*)d_in[10];
  const float* W1b = (const float*)d_in[11];
  const float* b1b = (const float*)d_in[12];
  const float* W1c = (const float*)d_in[13];
  const float* b1c = (const float*)d_in[14];
  float* out = (float*)d_out;

  char* ws = (char*)d_ws;
  size_t off = 0;
  auto alloc = [&](size_t bytes) -> char* {
    char* p = ws + off; off += (bytes + 255) & ~(size_t)255; return p;
  };
  // persistent
  unsigned short* W1bT = (unsigned short*)alloc(2048ull * 1024 * 2);  // [2048][1024]
  unsigned short* W1cT = (unsigned short*)alloc(128ull * 2048 * 2);   // [128][2048]
  float*          V1   = (float*)alloc(2048ull * 1024 * 4);           // v2s @ W1a
  float*          A1p  = (float*)alloc(2048ull * 1024 * 4);           // att @ W1a + b1a
  unsigned short* Pb   = (unsigned short*)alloc(133120ull * 128 * 2); // bf16 projections
  // overlay
  size_t O = off;
  off = O;
  unsigned short* W1aT = (unsigned short*)alloc(1024ull * 320 * 2);   // [1024][320]  (K-pad)
  unsigned short* v2sb = (unsigned short*)alloc(2048ull * 320 * 2);
  unsigned short* attb = (unsigned short*)alloc(2048ull * 320 * 2);
  unsigned short* W2bT = (unsigned short*)alloc(2048ull * 1024 * 2);
  unsigned short* W2cT = (unsigned short*)alloc(384ull * 2048 * 2);   // [384][2048]  (N-pad)
  unsigned short* h_a  = (unsigned short*)alloc(2048ull * 1024 * 2);
  unsigned short* h2a  = (unsigned short*)alloc(2048ull * 2048 * 2);
  size_t early_end = off;

  // ---- chunk plans: m-tiles (x256 rows) per chunk, sum = 520 (all row counts % 128 == 0)
  static const int plans[4][8] = {{260,260,0,0,0,0,0,0},
                                  {132,132,128,128,0,0,0,0},
                                  {130,130,130,130,0,0,0,0},
                                  {65,65,65,65,65,65,65,65}};
  int sel = -1, maxmt = 0;
  for (int p = 0; p < 4 && sel < 0; ++p) {
    int mx = 0;
    for (int i = 0; i < 8; ++i) if (plans[p][i] > mx) mx = plans[p][i];
    size_t rows = (size_t)mx * 256;
    size_t late = O + ((rows * 1024 * 2 + 255) & ~(size_t)255)
                    + ((rows * 2048 * 2 + 255) & ~(size_t)255);
    size_t need = late > early_end ? late : early_end;
    if (need <= ws_size) { sel = p; maxmt = mx; }
  }
  int fallR = 0;
  if (sel < 0) {   // NCH=16 fallback
    size_t rows = 133120ull / 16;
    size_t late = O + ((rows * 1024 * 2 + 255) & ~(size_t)255)
                    + ((rows * 2048 * 2 + 255) & ~(size_t)255);
    size_t need = late > early_end ? late : early_end;
    if (need <= ws_size) fallR = (int)rows;
  }
  fprintf(stderr, "[kernel_launch] ws_size=%zu sel=%d\n", ws_size, sel);
  if (sel < 0 && !fallR) {
    hipMemsetAsync(d_out, 0, (size_t)out_size * 4, stream);
    return;
  }
  off = O;
  size_t bufrows = (sel >= 0) ? (size_t)maxmt * 256 : (size_t)fallR;
  unsigned short* H1c = (unsigned short*)alloc(bufrows * 1024 * 2);
  unsigned short* H2c = (unsigned short*)alloc(bufrows * 2048 * 2);

  dim3 blk(256);
  // weight prep (tiled coalesced transpose)
  k_transpose_cast_t<<<dim3(16, 32), blk, 0, stream>>>(W2b, W2bT, 2048, 1024, 1024);
  k_transpose_cast_t<<<dim3(32, 6),  blk, 0, stream>>>(W2c, W2cT, 312, 2048, 2048);
  k_transpose_cast_t<<<dim3(5, 16),  blk, 0, stream>>>(W1a, W1aT, 1024, 312, 320);
  k_transpose_cast_t<<<dim3(16, 32), blk, 0, stream>>>(W1b, W1bT, 2048, 1024, 1024);
  k_transpose_cast_t<<<dim3(32, 2),  blk, 0, stream>>>(W1c, W1cT, 128, 2048, 2048);
  k_att_l1<<<8192, blk, 0, stream>>>(tar, W2a, b2a, h_a);
  k_v2s_cast<<<2560, blk, 0, stream>>>(v2s, v2sb);
  // att MLP
  k_gemm_bt<true,  true ><<<256, blk, 0, stream>>>(h_a,  W2bT, b2b, 2048, 16, 2048, 1024, h2a,  2048, 1);
  k_gemm_bt<true,  true ><<<48,  blk, 0, stream>>>(h2a,  W2cT, b2c, 312,  3,  320,  2048, attb, 320,  1);
  // layer-1 factored
  k_gemm_bt<false, false><<<128, blk, 0, stream>>>(v2sb, W1aT, nullptr, 0,  8, 1024, 320, V1,  1024, 1);
  k_gemm_bt<false, false><<<128, blk, 0, stream>>>(attb, W1aT, b1a, 1024,  8, 1024, 320, A1p, 1024, 1);
  // chunked: build H1 -> layer2 -> layer3
  if (sel >= 0) {
    int rbase = 0;
    for (int i = 0; i < 8 && plans[sel][i]; ++i) {
      int R = plans[sel][i] * 256;
      k_build_h1<<<R, blk, 0, stream>>>(V1, A1p, sidx, H1c, rbase);
      k_gemm_bt<true, true><<<(R / 128) * 16, blk, 0, stream>>>(H1c, W1bT, b1b, 2048, 16, 2048, 1024, H2c, 2048, 1);
      k_gemm_bt<true, true><<<(R / 128), blk, 0, stream>>>(H2c, W1cT, b1c, 128, 1, 128, 2048,
                                                            Pb + (size_t)rbase * 128, 128, 0);
      rbase += R;
    }
  } else {
    for (int c = 0; c < 16; ++c) {
      int rbase = c * fallR;
      k_build_h1<<<fallR, blk, 0, stream>>>(V1, A1p, sidx, H1c, rbase);
      k_gemm_bt<true, true><<<(fallR / 128) * 16, blk, 0, stream>>>(H1c, W1bT, b1b, 2048, 16, 2048, 1024, H2c, 2048, 1);
      k_gemm_bt<true, true><<<(fallR / 128), blk, 0, stream>>>(H2c, W1cT, b1c, 128, 1, 128, 2048,
                                                                Pb + (size_t)rbase * 128, 128, 0);
    }
  }
  // logits
  k_dot<<<2048, blk, 0, stream>>>(Pb, out);
}